// Round 1
// baseline (5346.418 us; speedup 1.0000x reference)
//
#include <hip/hip_runtime.h>

#define DINL static __device__ __forceinline__

namespace {
constexpr int BN = 16;
constexpr int LQ = 2048;
constexpr int DM = 64;
constexpr int DI = 128;
constexpr float EPS = 1e-5f;
}

DINL float sigmoidf_(float x) { return 1.0f / (1.0f + __expf(-x)); }

// ---------------- Stage A: conv1d 1->64 K=3 pad1 + BN + ReLU -> h1 (B,64,L)
__global__ void __launch_bounds__(256) k_front(const float* __restrict__ x,
    const float* __restrict__ w, const float* __restrict__ bb,
    const float* __restrict__ g, const float* __restrict__ be,
    float* __restrict__ h1) {
  int idx = blockIdx.x * 256 + threadIdx.x;   // (b*64+c)*2048 + l
  int l = idx & (LQ - 1);
  int c = (idx >> 11) & 63;
  int b = idx >> 17;
  const float* xr = x + b * LQ;
  float xm = (l > 0) ? xr[l - 1] : 0.0f;
  float x0 = xr[l];
  float xp = (l < LQ - 1) ? xr[l + 1] : 0.0f;
  float acc = w[c * 3 + 0] * xm + w[c * 3 + 1] * x0 + w[c * 3 + 2] * xp + bb[c];
  float v = acc * (g[c] * rsqrtf(1.0f + EPS)) + be[c];
  h1[idx] = fmaxf(v, 0.0f);
}

// ---------------- Stage B: conv1d 64->64 K=3 pad1 + BN + ReLU, write transposed res (B,L,64)
__global__ void __launch_bounds__(256) k_conv2(const float* __restrict__ h1,
    const float* __restrict__ w, const float* __restrict__ bb,
    const float* __restrict__ g, const float* __restrict__ be,
    float* __restrict__ res) {
  __shared__ float xin[64 * 66];   // 64 ci x (64+2)
  __shared__ float wl[32 * 192];   // half the out channels per pass
  __shared__ float os[64 * 65];    // out staging (l, c) padded
  int tid = threadIdx.x;
  int b = blockIdx.x >> 5;
  int t0 = (blockIdx.x & 31) * 64;
  for (int i = tid; i < 64 * 66; i += 256) {
    int ci = i / 66, j = i % 66;
    int l = t0 - 1 + j;
    xin[i] = (l >= 0 && l < LQ) ? h1[(b * 64 + ci) * LQ + l] : 0.0f;
  }
  int wv = tid >> 6, lane = tid & 63;
  float rs = rsqrtf(1.0f + EPS);
  for (int p = 0; p < 2; ++p) {
    __syncthreads();
    for (int i = tid; i < 32 * 192; i += 256) wl[i] = w[p * 32 * 192 + i];
    __syncthreads();
    float acc[8];
#pragma unroll
    for (int i2 = 0; i2 < 8; ++i2) acc[i2] = 0.0f;
    for (int ci = 0; ci < 64; ++ci) {
      float x0 = xin[ci * 66 + lane];
      float x1 = xin[ci * 66 + lane + 1];
      float x2 = xin[ci * 66 + lane + 2];
      const float* wr = &wl[(wv * 8) * 192 + ci * 3];
#pragma unroll
      for (int i2 = 0; i2 < 8; ++i2)
        acc[i2] += wr[i2 * 192 + 0] * x0 + wr[i2 * 192 + 1] * x1 + wr[i2 * 192 + 2] * x2;
    }
#pragma unroll
    for (int i2 = 0; i2 < 8; ++i2) {
      int co = p * 32 + wv * 8 + i2;
      float v = (acc[i2] + bb[co]) * (g[co] * rs) + be[co];
      os[lane * 65 + co] = fmaxf(v, 0.0f);
    }
  }
  __syncthreads();
  for (int i = tid; i < 4096; i += 256) {
    int r = i >> 6, c = i & 63;
    res[(b * LQ + t0 + r) * 64 + c] = os[r * 65 + c];
  }
}

// ---------------- Mamba K1: LayerNorm + in_proj (256x64), split to xi_raw / z
__global__ void __launch_bounds__(256) k_lnproj(const float* __restrict__ res,
    const float* __restrict__ lng, const float* __restrict__ lnb,
    const float* __restrict__ inw, float* __restrict__ xiraw, float* __restrict__ zb) {
  __shared__ float tile[64 * 68];     // rows padded to 68 (16B aligned)
  __shared__ float4 w4[16 * 128];     // w4[kb*128 + c] : contiguous per-lane reads
  __shared__ float gl[64], bl[64], mA[64], ivA[64];
  int tid = threadIdx.x;
  int b = blockIdx.x >> 5;
  int t0 = (blockIdx.x & 31) * 64;
  const float* rb0 = res + (size_t)(b * LQ + t0) * 64;
  for (int i = tid; i < 1024; i += 256) {
    int r = i >> 4, kb = i & 15;
    *(float4*)&tile[r * 68 + kb * 4] = ((const float4*)rb0)[i];
  }
  if (tid < 64) gl[tid] = lng[tid];
  else if (tid < 128) bl[tid - 64] = lnb[tid - 64];
  __syncthreads();
  if (tid < 64) {
    float s = 0.0f;
#pragma unroll
    for (int k = 0; k < 64; ++k) s += tile[tid * 68 + k];
    float m = s * (1.0f / 64.0f);
    float q = 0.0f;
#pragma unroll
    for (int k = 0; k < 64; ++k) { float dd = tile[tid * 68 + k] - m; q += dd * dd; }
    mA[tid] = m;
    ivA[tid] = rsqrtf(q * (1.0f / 64.0f) + EPS);
  }
  __syncthreads();
  for (int i = tid; i < 4096; i += 256) {
    int r = i >> 6, k = i & 63;
    tile[r * 68 + k] = (tile[r * 68 + k] - mA[r]) * ivA[r] * gl[k] + bl[k];
  }
  int wv = tid >> 6, lane = tid & 63;
  const float4* wsrc = (const float4*)inw;
  for (int p = 0; p < 2; ++p) {
    __syncthreads();
    for (int i = tid; i < 2048; i += 256) {
      int c = i >> 4, kb = i & 15;
      w4[kb * 128 + c] = wsrc[p * 2048 + i];
    }
    __syncthreads();
    float* outp = (p == 0) ? xiraw : zb;
    for (int ci = 0; ci < 2; ++ci) {
      int c = ci * 64 + lane;
      for (int rbk = 0; rbk < 2; ++rbk) {
        int r0 = wv * 16 + rbk * 8;
        float acc[8];
#pragma unroll
        for (int rr = 0; rr < 8; ++rr) acc[rr] = 0.0f;
        for (int kb = 0; kb < 16; ++kb) {
          float4 wvv = w4[kb * 128 + c];
#pragma unroll
          for (int rr = 0; rr < 8; ++rr) {
            float4 xv = *(const float4*)&tile[(r0 + rr) * 68 + kb * 4];
            acc[rr] += wvv.x * xv.x + wvv.y * xv.y + wvv.z * xv.z + wvv.w * xv.w;
          }
        }
#pragma unroll
        for (int rr = 0; rr < 8; ++rr)
          outp[(size_t)(b * LQ + t0 + r0 + rr) * DI + c] = acc[rr];
      }
    }
  }
}

// ---------------- Mamba K2: causal depthwise conv K=4 + SiLU + x_proj + dt_proj(softplus)
__global__ void __launch_bounds__(256) k_convx(const float* __restrict__ xiraw,
    const float* __restrict__ cw, const float* __restrict__ cb,
    const float* __restrict__ xw, const float* __restrict__ dtw,
    const float* __restrict__ dtbias, float* __restrict__ xib,
    float* __restrict__ dtb, float* __restrict__ bcb) {
  __shared__ float xin[35 * 128];
  __shared__ float xit[32 * 128];
  __shared__ float4 xw4[32 * 36];   // xw4[kb*36 + c]
  __shared__ float xdbl[32 * 40];
  __shared__ float4 cw4[128];
  __shared__ float cbl[128];
  __shared__ float4 dtw4[128];
  __shared__ float dtbl[128];
  int tid = threadIdx.x;
  int b = blockIdx.x >> 6;
  int t0 = (blockIdx.x & 63) * 32;
  for (int i = tid; i < 1120; i += 256) {     // 35*128/4 float4 loads
    int r = i >> 5, dq = i & 31;
    int l = t0 - 3 + r;
    float4 v = make_float4(0.f, 0.f, 0.f, 0.f);
    if (l >= 0) v = ((const float4*)xiraw)[(size_t)(b * LQ + l) * 32 + dq];
    *(float4*)&xin[r * 128 + dq * 4] = v;
  }
  if (tid < 128) {
    cw4[tid] = ((const float4*)cw)[tid];
    cbl[tid] = cb[tid];
    dtw4[tid] = ((const float4*)dtw)[tid];
    dtbl[tid] = dtbias[tid];
  }
  for (int i = tid; i < 32 * 36; i += 256) {
    xw4[(i & 31) * 36 + (i >> 5)] = ((const float4*)xw)[i];
  }
  __syncthreads();
  for (int i = tid; i < 32 * 128; i += 256) {
    int r = i >> 7, d = i & 127;
    float4 cv = cw4[d];
    float a = cbl[d] + cv.x * xin[r * 128 + d] + cv.y * xin[(r + 1) * 128 + d]
            + cv.z * xin[(r + 2) * 128 + d] + cv.w * xin[(r + 3) * 128 + d];
    float v = a * sigmoidf_(a);
    xit[i] = v;
    xib[(size_t)(b * LQ + t0 + r) * DI + d] = v;
  }
  __syncthreads();
  int wv = tid >> 6, lane = tid & 63;
  if (lane < 36) {
    int r0 = wv * 8;
    float acc[8];
#pragma unroll
    for (int rr = 0; rr < 8; ++rr) acc[rr] = 0.0f;
    for (int kb = 0; kb < 32; ++kb) {
      float4 wvv = xw4[kb * 36 + lane];
#pragma unroll
      for (int rr = 0; rr < 8; ++rr) {
        float4 xv = *(const float4*)&xit[(r0 + rr) * 128 + kb * 4];
        acc[rr] += wvv.x * xv.x + wvv.y * xv.y + wvv.z * xv.z + wvv.w * xv.w;
      }
    }
#pragma unroll
    for (int rr = 0; rr < 8; ++rr) xdbl[(r0 + rr) * 40 + lane] = acc[rr];
  }
  __syncthreads();
  for (int i = tid; i < 32 * 128; i += 256) {
    int r = i >> 7, d = i & 127;
    float4 wvv = dtw4[d];
    float4 xd = *(const float4*)&xdbl[r * 40];
    float sv = dtbl[d] + wvv.x * xd.x + wvv.y * xd.y + wvv.z * xd.z + wvv.w * xd.w;
    dtb[(size_t)(b * LQ + t0 + r) * DI + d] = (sv > 20.0f) ? sv : log1pf(__expf(sv));
  }
  for (int i = tid; i < 32 * 32; i += 256) {
    int r = i >> 5, j = i & 31;
    bcb[(size_t)(b * LQ + t0 + r) * 32 + j] = xdbl[r * 40 + 4 + j];
  }
}

// ---------------- Mamba K3: selective scan. 16 lanes (states) per (b,d). ys overwrites dtb.
__global__ void __launch_bounds__(256) k_scan(float* __restrict__ dtb,
    const float* __restrict__ xib, const float* __restrict__ bcb,
    const float* __restrict__ alog) {
  int tg = blockIdx.x * 256 + threadIdx.x;
  int grp = tg >> 4;          // (b,d)
  int b = grp >> 7, d = grp & 127;
  int j = tg & 15;
  float A2 = -__expf(alog[d * 16 + j]) * 1.4426950408889634f;  // for exp2
  const float* pdt = dtb + b * LQ * DI + d;
  const float* px = xib + b * LQ * DI + d;
  const float* pbc = bcb + b * LQ * 32;
  float* py = dtb + b * LQ * DI + d;
  float s = 0.0f;
#pragma unroll 4
  for (int t = 0; t < LQ; ++t) {
    float dtv = pdt[t * DI];
    float xv = px[t * DI];
    float Bv = pbc[t * 32 + j];
    float Cv = pbc[t * 32 + 16 + j];
    float a = exp2f(dtv * A2);
    s = a * s + (dtv * xv) * Bv;
    float p = s * Cv;
    p += __shfl_xor(p, 1);
    p += __shfl_xor(p, 2);
    p += __shfl_xor(p, 4);
    p += __shfl_xor(p, 8);
    if (j == 0) py[t * DI] = p;
  }
}

// ---------------- Mamba K4: y = ys + xi*Dp; gate with silu(z); out_proj (64x128); res +=
__global__ void __launch_bounds__(256) k_gate(const float* __restrict__ ys,
    const float* __restrict__ xib, const float* __restrict__ zb,
    const float* __restrict__ Dpl, const float* __restrict__ outw,
    float* __restrict__ res) {
  __shared__ float gt[64 * 128];
  __shared__ float4 w4[16 * 64];   // half the kb range per pass
  int tid = threadIdx.x;
  int b = blockIdx.x >> 5;
  int t0 = (blockIdx.x & 31) * 64;
  size_t base = (size_t)(b * LQ + t0) * DI;
  const float4* ys4 = (const float4*)(ys + base);
  const float4* xi4 = (const float4*)(xib + base);
  const float4* zb4 = (const float4*)(zb + base);
  const float4* dp4 = (const float4*)Dpl;
  for (int i = tid; i < 2048; i += 256) {
    float4 yv = ys4[i], xv = xi4[i], zv = zb4[i];
    float4 dp = dp4[i & 31];
    float4 o;
    o.x = (yv.x + xv.x * dp.x) * zv.x * sigmoidf_(zv.x);
    o.y = (yv.y + xv.y * dp.y) * zv.y * sigmoidf_(zv.y);
    o.z = (yv.z + xv.z * dp.z) * zv.z * sigmoidf_(zv.z);
    o.w = (yv.w + xv.w * dp.w) * zv.w * sigmoidf_(zv.w);
    *(float4*)&gt[i * 4] = o;
  }
  int wv = tid >> 6, lane = tid & 63;
  float acc[2][8];
#pragma unroll
  for (int rb = 0; rb < 2; ++rb)
#pragma unroll
    for (int rr = 0; rr < 8; ++rr) acc[rb][rr] = 0.0f;
  for (int h = 0; h < 2; ++h) {
    __syncthreads();
    for (int i = tid; i < 1024; i += 256) {
      int c = i >> 4, kb = i & 15;
      w4[kb * 64 + c] = ((const float4*)outw)[c * 32 + h * 16 + kb];
    }
    __syncthreads();
    for (int rb = 0; rb < 2; ++rb) {
      int r0 = wv * 16 + rb * 8;
      for (int kb = 0; kb < 16; ++kb) {
        float4 wvv = w4[kb * 64 + lane];
        int kk = (h * 16 + kb) * 4;
#pragma unroll
        for (int rr = 0; rr < 8; ++rr) {
          float4 xv = *(const float4*)&gt[(r0 + rr) * 128 + kk];
          acc[rb][rr] += wvv.x * xv.x + wvv.y * xv.y + wvv.z * xv.z + wvv.w * xv.w;
        }
      }
    }
  }
#pragma unroll
  for (int rb = 0; rb < 2; ++rb)
#pragma unroll
    for (int rr = 0; rr < 8; ++rr)
      res[(size_t)(b * LQ + t0 + wv * 16 + rb * 8 + rr) * 64 + lane] += acc[rb][rr];
}

// ---------------- Final LayerNorm: res -> hf, one wave per row
__global__ void __launch_bounds__(256) k_lnfinal(const float* __restrict__ res,
    const float* __restrict__ g, const float* __restrict__ bb, float* __restrict__ hf) {
  int row = blockIdx.x * 4 + (threadIdx.x >> 6);
  int lane = threadIdx.x & 63;
  float v = res[row * 64 + lane];
  float s = v;
#pragma unroll
  for (int m = 32; m >= 1; m >>= 1) s += __shfl_xor(s, m);
  float mean = s * (1.0f / 64.0f);
  float dd = v - mean;
  float q = dd * dd;
#pragma unroll
  for (int m = 32; m >= 1; m >>= 1) q += __shfl_xor(q, m);
  float iv = rsqrtf(q * (1.0f / 64.0f) + EPS);
  hf[row * 64 + lane] = dd * iv * g[lane] + bb[lane];
}

// ---------------- Classifier conv: 64->64 K=5 stride2 pad2 + BN + ReLU
// layout 0: input (B, Lin, 64) interleaved; layout 1: input (B, 64, Lin)
__global__ void __launch_bounds__(256) k_cls(const float* __restrict__ in,
    float* __restrict__ out, const float* __restrict__ w,
    const float* __restrict__ bb, const float* __restrict__ g,
    const float* __restrict__ be, int Lin, int Lout, int layout) {
  __shared__ float xin[64 * 136];   // 64 ci x 131 (span), padded
  __shared__ float wl[16 * 320];    // 16 out-ch per pass
  int tid = threadIdx.x;
  int tilesPerB = Lout >> 6;
  int b = blockIdx.x / tilesPerB;
  int t0 = (blockIdx.x % tilesPerB) * 64;
  int lbase = 2 * t0 - 2;
  if (layout == 0) {
    for (int i = tid; i < 64 * 131; i += 256) {
      int lr = i >> 6, ci = i & 63;
      int l = lbase + lr;
      xin[ci * 136 + lr] = (l >= 0 && l < Lin) ? in[(b * Lin + l) * 64 + ci] : 0.0f;
    }
  } else {
    for (int i = tid; i < 64 * 132; i += 256) {
      int ci = i / 132, lr = i % 132;
      if (lr < 131) {
        int l = lbase + lr;
        xin[ci * 136 + lr] = (l >= 0 && l < Lin) ? in[(b * 64 + ci) * Lin + l] : 0.0f;
      }
    }
  }
  int wv = tid >> 6, lane = tid & 63;
  float rs = rsqrtf(1.0f + EPS);
  for (int p = 0; p < 4; ++p) {
    __syncthreads();
    for (int i = tid; i < 16 * 320; i += 256) wl[i] = w[p * 16 * 320 + i];
    __syncthreads();
    float acc[4] = {0.0f, 0.0f, 0.0f, 0.0f};
    for (int ci = 0; ci < 64; ++ci) {
      const float* xr = &xin[ci * 136 + 2 * lane];
      float v0 = xr[0], v1 = xr[1], v2 = xr[2], v3 = xr[3], v4 = xr[4];
      const float* wr = &wl[(wv * 4) * 320 + ci * 5];
#pragma unroll
      for (int i2 = 0; i2 < 4; ++i2) {
        acc[i2] += wr[i2 * 320 + 0] * v0 + wr[i2 * 320 + 1] * v1 + wr[i2 * 320 + 2] * v2
                 + wr[i2 * 320 + 3] * v3 + wr[i2 * 320 + 4] * v4;
      }
    }
#pragma unroll
    for (int i2 = 0; i2 < 4; ++i2) {
      int co = p * 16 + wv * 4 + i2;
      float v = (acc[i2] + bb[co]) * (g[co] * rs) + be[co];
      out[(b * 64 + co) * Lout + t0 + lane] = fmaxf(v, 0.0f);
    }
  }
}

// ---------------- fc1 weight transpose prep: wt4[kb*256 + f] = w[f][4kb..4kb+3]
__global__ void __launch_bounds__(256) k_prep_fc1(const float* __restrict__ w,
                                                  float* __restrict__ wt) {
  int i = blockIdx.x * 256 + threadIdx.x;   // i < 131072
  int kb = i >> 8, f = i & 255;
  ((float4*)wt)[i] = ((const float4*)w)[f * 512 + kb];
}

// ---------------- Pool + FC1 + BN + ReLU + FC2
__global__ void __launch_bounds__(256) k_fc(const float* __restrict__ cin,
    const float* __restrict__ w1t, const float* __restrict__ b1,
    const float* __restrict__ g, const float* __restrict__ be,
    const float* __restrict__ w2, const float* __restrict__ b2,
    float* __restrict__ dout) {
  __shared__ float pooled[2048];
  __shared__ float feat[256];
  int tid = threadIdx.x;
  int b = blockIdx.x;
  for (int i = tid; i < 2048; i += 256) {
    float4 v = ((const float4*)cin)[b * 2048 + i];
    pooled[i] = (v.x + v.y + v.z + v.w) * 0.25f;
  }
  __syncthreads();
  float acc = b1[tid];
  const float4* wt4 = (const float4*)w1t;
  for (int kb = 0; kb < 512; ++kb) {
    float4 wv = wt4[kb * 256 + tid];
    float4 pv = *(const float4*)&pooled[kb * 4];
    acc += wv.x * pv.x + wv.y * pv.y + wv.z * pv.z + wv.w * pv.w;
  }
  float v = acc * (g[tid] * rsqrtf(1.0f + EPS)) + be[tid];
  feat[tid] = fmaxf(v, 0.0f);
  __syncthreads();
  if (tid < 5) {
    float a2 = b2[tid];
    for (int k = 0; k < 256; ++k) a2 += w2[tid * 256 + k] * feat[k];
    dout[b * 5 + tid] = a2;
  }
}

extern "C" void kernel_launch(void* const* d_in, const int* in_sizes, int n_in,
                              void* d_out, int out_size, void* d_ws, size_t ws_size,
                              hipStream_t stream) {
  (void)in_sizes; (void)n_in; (void)out_size; (void)ws_size;
  const float* x      = (const float*)d_in[0];
  const float* dw1    = (const float*)d_in[1];
  const float* db1    = (const float*)d_in[2];
  const float* dg1    = (const float*)d_in[3];
  const float* dbe1   = (const float*)d_in[4];
  const float* dw2    = (const float*)d_in[5];
  const float* db2    = (const float*)d_in[6];
  const float* dg2    = (const float*)d_in[7];
  const float* dbe2   = (const float*)d_in[8];
  const float* lng    = (const float*)d_in[9];
  const float* lnb    = (const float*)d_in[10];
  const float* inw    = (const float*)d_in[11];
  const float* convw  = (const float*)d_in[12];
  const float* convb  = (const float*)d_in[13];
  const float* xprojw = (const float*)d_in[14];
  const float* dtpw   = (const float*)d_in[15];
  const float* dtpb   = (const float*)d_in[16];
  const float* alog   = (const float*)d_in[17];
  const float* Dp     = (const float*)d_in[18];
  const float* outw   = (const float*)d_in[19];
  const float* flng   = (const float*)d_in[20];
  const float* flnb   = (const float*)d_in[21];
  const float* clsw1  = (const float*)d_in[22];
  const float* clsb1  = (const float*)d_in[23];
  const float* clsg1  = (const float*)d_in[24];
  const float* clsbe1 = (const float*)d_in[25];
  const float* clswR  = (const float*)d_in[26];
  const float* clsbR  = (const float*)d_in[27];
  const float* clsgR  = (const float*)d_in[28];
  const float* clsbeR = (const float*)d_in[29];
  const float* fc1w   = (const float*)d_in[30];
  const float* fc1b   = (const float*)d_in[31];
  const float* fcg    = (const float*)d_in[32];
  const float* fcbe   = (const float*)d_in[33];
  const float* fc2w   = (const float*)d_in[34];
  const float* fc2b   = (const float*)d_in[35];

  float* ws = (float*)d_ws;
  float* h1    = ws;                    // 2,097,152  (B,64,L); reused as hf later
  float* res   = ws + 2097152;          // 2,097,152  (B,L,64)
  float* xiraw = ws + 4194304;          // 4,194,304  (B,L,128); cls bufs reuse
  float* zb    = ws + 8388608;          // 4,194,304
  float* xib   = ws + 12582912;         // 4,194,304
  float* dtb   = ws + 16777216;         // 4,194,304  (dt, overwritten by ys in scan)
  float* bcb   = ws + 20971520;         // 1,048,576  (B,L,32)
  float* fc1t  = ws + 22020096;         // 524,288
  // classifier buffers reuse xiraw region (free after mamba layers)
  float* c1 = xiraw;
  float* c2 = xiraw + 1048576;
  float* c3 = xiraw + 1572864;
  float* c4 = xiraw + 1835008;
  float* hf = h1;

  k_prep_fc1<<<512, 256, 0, stream>>>(fc1w, fc1t);
  k_front<<<8192, 256, 0, stream>>>(x, dw1, db1, dg1, dbe1, h1);
  k_conv2<<<512, 256, 0, stream>>>(h1, dw2, db2, dg2, dbe2, res);
  for (int il = 0; il < 4; ++il) {
    k_lnproj<<<512, 256, 0, stream>>>(res, lng + il * 64, lnb + il * 64,
                                      inw + il * 16384, xiraw, zb);
    k_convx<<<1024, 256, 0, stream>>>(xiraw, convw + il * 512, convb + il * 128,
                                      xprojw + il * 4608, dtpw + il * 512,
                                      dtpb + il * 128, xib, dtb, bcb);
    k_scan<<<128, 256, 0, stream>>>(dtb, xib, bcb, alog + il * 2048);
    k_gate<<<512, 256, 0, stream>>>(dtb, xib, zb, Dp + il * 128,
                                    outw + il * 8192, res);
  }
  k_lnfinal<<<8192, 256, 0, stream>>>(res, flng, flnb, hf);
  k_cls<<<256, 256, 0, stream>>>(hf, c1, clsw1, clsb1, clsg1, clsbe1, 2048, 1024, 0);
  k_cls<<<128, 256, 0, stream>>>(c1, c2, clswR + 0 * 20480, clsbR + 0, clsgR + 0,
                                 clsbeR + 0, 1024, 512, 1);
  k_cls<<<64, 256, 0, stream>>>(c2, c3, clswR + 1 * 20480, clsbR + 64, clsgR + 64,
                                clsbeR + 64, 512, 256, 1);
  k_cls<<<32, 256, 0, stream>>>(c3, c4, clswR + 2 * 20480, clsbR + 128, clsgR + 128,
                                clsbeR + 128, 256, 128, 1);
  k_fc<<<16, 256, 0, stream>>>(c4, fc1t, fc1b, fcg, fcbe, fc2w, fc2b, (float*)d_out);
}

// Round 2
// 2097.250 us; speedup vs baseline: 2.5493x; 2.5493x over previous
//
#include <hip/hip_runtime.h>

#define DINL static __device__ __forceinline__

namespace {
constexpr int BN = 16;
constexpr int LQ = 2048;
constexpr int DM = 64;
constexpr int DI = 128;
constexpr float EPS = 1e-5f;
constexpr int NCH = 32;   // scan chunks
constexpr int CT = 64;    // chunk length (NCH*CT == LQ)
}

DINL float sigmoidf_(float x) { return 1.0f / (1.0f + __expf(-x)); }

// ---------------- Stage A: conv1d 1->64 K=3 pad1 + BN + ReLU -> h1 (B,64,L)
__global__ void __launch_bounds__(256) k_front(const float* __restrict__ x,
    const float* __restrict__ w, const float* __restrict__ bb,
    const float* __restrict__ g, const float* __restrict__ be,
    float* __restrict__ h1) {
  int idx = blockIdx.x * 256 + threadIdx.x;   // (b*64+c)*2048 + l
  int l = idx & (LQ - 1);
  int c = (idx >> 11) & 63;
  int b = idx >> 17;
  const float* xr = x + b * LQ;
  float xm = (l > 0) ? xr[l - 1] : 0.0f;
  float x0 = xr[l];
  float xp = (l < LQ - 1) ? xr[l + 1] : 0.0f;
  float acc = w[c * 3 + 0] * xm + w[c * 3 + 1] * x0 + w[c * 3 + 2] * xp + bb[c];
  float v = acc * (g[c] * rsqrtf(1.0f + EPS)) + be[c];
  h1[idx] = fmaxf(v, 0.0f);
}

// ---------------- Stage B: conv1d 64->64 K=3 pad1 + BN + ReLU, write transposed res (B,L,64)
__global__ void __launch_bounds__(256) k_conv2(const float* __restrict__ h1,
    const float* __restrict__ w, const float* __restrict__ bb,
    const float* __restrict__ g, const float* __restrict__ be,
    float* __restrict__ res) {
  __shared__ float xin[64 * 66];   // 64 ci x (64+2)
  __shared__ float wl[32 * 192];   // half the out channels per pass
  __shared__ float os[64 * 65];    // out staging (l, c) padded
  int tid = threadIdx.x;
  int b = blockIdx.x >> 5;
  int t0 = (blockIdx.x & 31) * 64;
  for (int i = tid; i < 64 * 66; i += 256) {
    int ci = i / 66, j = i % 66;
    int l = t0 - 1 + j;
    xin[i] = (l >= 0 && l < LQ) ? h1[(b * 64 + ci) * LQ + l] : 0.0f;
  }
  int wv = tid >> 6, lane = tid & 63;
  float rs = rsqrtf(1.0f + EPS);
  for (int p = 0; p < 2; ++p) {
    __syncthreads();
    for (int i = tid; i < 32 * 192; i += 256) wl[i] = w[p * 32 * 192 + i];
    __syncthreads();
    float acc[8];
#pragma unroll
    for (int i2 = 0; i2 < 8; ++i2) acc[i2] = 0.0f;
    for (int ci = 0; ci < 64; ++ci) {
      float x0 = xin[ci * 66 + lane];
      float x1 = xin[ci * 66 + lane + 1];
      float x2 = xin[ci * 66 + lane + 2];
      const float* wr = &wl[(wv * 8) * 192 + ci * 3];
#pragma unroll
      for (int i2 = 0; i2 < 8; ++i2)
        acc[i2] += wr[i2 * 192 + 0] * x0 + wr[i2 * 192 + 1] * x1 + wr[i2 * 192 + 2] * x2;
    }
#pragma unroll
    for (int i2 = 0; i2 < 8; ++i2) {
      int co = p * 32 + wv * 8 + i2;
      float v = (acc[i2] + bb[co]) * (g[co] * rs) + be[co];
      os[lane * 65 + co] = fmaxf(v, 0.0f);
    }
  }
  __syncthreads();
  for (int i = tid; i < 4096; i += 256) {
    int r = i >> 6, c = i & 63;
    res[(b * LQ + t0 + r) * 64 + c] = os[r * 65 + c];
  }
}

// ---------------- Mamba K1: LayerNorm + in_proj (256x64), split to xi_raw / z
__global__ void __launch_bounds__(256) k_lnproj(const float* __restrict__ res,
    const float* __restrict__ lng, const float* __restrict__ lnb,
    const float* __restrict__ inw, float* __restrict__ xiraw, float* __restrict__ zb) {
  __shared__ float tile[64 * 68];     // rows padded to 68 (16B aligned)
  __shared__ float4 w4[16 * 128];     // w4[kb*128 + c] : contiguous per-lane reads
  __shared__ float gl[64], bl[64], mA[64], ivA[64];
  int tid = threadIdx.x;
  int b = blockIdx.x >> 5;
  int t0 = (blockIdx.x & 31) * 64;
  const float* rb0 = res + (size_t)(b * LQ + t0) * 64;
  for (int i = tid; i < 1024; i += 256) {
    int r = i >> 4, kb = i & 15;
    *(float4*)&tile[r * 68 + kb * 4] = ((const float4*)rb0)[i];
  }
  if (tid < 64) gl[tid] = lng[tid];
  else if (tid < 128) bl[tid - 64] = lnb[tid - 64];
  __syncthreads();
  if (tid < 64) {
    float s = 0.0f;
#pragma unroll
    for (int k = 0; k < 64; ++k) s += tile[tid * 68 + k];
    float m = s * (1.0f / 64.0f);
    float q = 0.0f;
#pragma unroll
    for (int k = 0; k < 64; ++k) { float dd = tile[tid * 68 + k] - m; q += dd * dd; }
    mA[tid] = m;
    ivA[tid] = rsqrtf(q * (1.0f / 64.0f) + EPS);
  }
  __syncthreads();
  for (int i = tid; i < 4096; i += 256) {
    int r = i >> 6, k = i & 63;
    tile[r * 68 + k] = (tile[r * 68 + k] - mA[r]) * ivA[r] * gl[k] + bl[k];
  }
  int wv = tid >> 6, lane = tid & 63;
  const float4* wsrc = (const float4*)inw;
  for (int p = 0; p < 2; ++p) {
    __syncthreads();
    for (int i = tid; i < 2048; i += 256) {
      int c = i >> 4, kb = i & 15;
      w4[kb * 128 + c] = wsrc[p * 2048 + i];
    }
    __syncthreads();
    float* outp = (p == 0) ? xiraw : zb;
    for (int ci = 0; ci < 2; ++ci) {
      int c = ci * 64 + lane;
      for (int rbk = 0; rbk < 2; ++rbk) {
        int r0 = wv * 16 + rbk * 8;
        float acc[8];
#pragma unroll
        for (int rr = 0; rr < 8; ++rr) acc[rr] = 0.0f;
        for (int kb = 0; kb < 16; ++kb) {
          float4 wvv = w4[kb * 128 + c];
#pragma unroll
          for (int rr = 0; rr < 8; ++rr) {
            float4 xv = *(const float4*)&tile[(r0 + rr) * 68 + kb * 4];
            acc[rr] += wvv.x * xv.x + wvv.y * xv.y + wvv.z * xv.z + wvv.w * xv.w;
          }
        }
#pragma unroll
        for (int rr = 0; rr < 8; ++rr)
          outp[(size_t)(b * LQ + t0 + r0 + rr) * DI + c] = acc[rr];
      }
    }
  }
}

// ---------------- Mamba K2: causal depthwise conv K=4 + SiLU + x_proj + dt_proj(softplus)
__global__ void __launch_bounds__(256) k_convx(const float* __restrict__ xiraw,
    const float* __restrict__ cw, const float* __restrict__ cb,
    const float* __restrict__ xw, const float* __restrict__ dtw,
    const float* __restrict__ dtbias, float* __restrict__ xib,
    float* __restrict__ dtb, float* __restrict__ bcb) {
  __shared__ float xin[35 * 128];
  __shared__ float xit[32 * 128];
  __shared__ float4 xw4[32 * 36];   // xw4[kb*36 + c]
  __shared__ float xdbl[32 * 40];
  __shared__ float4 cw4[128];
  __shared__ float cbl[128];
  __shared__ float4 dtw4[128];
  __shared__ float dtbl[128];
  int tid = threadIdx.x;
  int b = blockIdx.x >> 6;
  int t0 = (blockIdx.x & 63) * 32;
  for (int i = tid; i < 1120; i += 256) {     // 35*128/4 float4 loads
    int r = i >> 5, dq = i & 31;
    int l = t0 - 3 + r;
    float4 v = make_float4(0.f, 0.f, 0.f, 0.f);
    if (l >= 0) v = ((const float4*)xiraw)[(size_t)(b * LQ + l) * 32 + dq];
    *(float4*)&xin[r * 128 + dq * 4] = v;
  }
  if (tid < 128) {
    cw4[tid] = ((const float4*)cw)[tid];
    cbl[tid] = cb[tid];
    dtw4[tid] = ((const float4*)dtw)[tid];
    dtbl[tid] = dtbias[tid];
  }
  for (int i = tid; i < 32 * 36; i += 256) {
    xw4[(i & 31) * 36 + (i >> 5)] = ((const float4*)xw)[i];
  }
  __syncthreads();
  for (int i = tid; i < 32 * 128; i += 256) {
    int r = i >> 7, d = i & 127;
    float4 cv = cw4[d];
    float a = cbl[d] + cv.x * xin[r * 128 + d] + cv.y * xin[(r + 1) * 128 + d]
            + cv.z * xin[(r + 2) * 128 + d] + cv.w * xin[(r + 3) * 128 + d];
    float v = a * sigmoidf_(a);
    xit[i] = v;
    xib[(size_t)(b * LQ + t0 + r) * DI + d] = v;
  }
  __syncthreads();
  int wv = tid >> 6, lane = tid & 63;
  if (lane < 36) {
    int r0 = wv * 8;
    float acc[8];
#pragma unroll
    for (int rr = 0; rr < 8; ++rr) acc[rr] = 0.0f;
    for (int kb = 0; kb < 32; ++kb) {
      float4 wvv = xw4[kb * 36 + lane];
#pragma unroll
      for (int rr = 0; rr < 8; ++rr) {
        float4 xv = *(const float4*)&xit[(r0 + rr) * 128 + kb * 4];
        acc[rr] += wvv.x * xv.x + wvv.y * xv.y + wvv.z * xv.z + wvv.w * xv.w;
      }
    }
#pragma unroll
    for (int rr = 0; rr < 8; ++rr) xdbl[(r0 + rr) * 40 + lane] = acc[rr];
  }
  __syncthreads();
  for (int i = tid; i < 32 * 128; i += 256) {
    int r = i >> 7, d = i & 127;
    float4 wvv = dtw4[d];
    float4 xd = *(const float4*)&xdbl[r * 40];
    float sv = dtbl[d] + wvv.x * xd.x + wvv.y * xd.y + wvv.z * xd.z + wvv.w * xd.w;
    dtb[(size_t)(b * LQ + t0 + r) * DI + d] = (sv > 20.0f) ? sv : log1pf(__expf(sv));
  }
  for (int i = tid; i < 32 * 32; i += 256) {
    int r = i >> 5, j = i & 31;
    bcb[(size_t)(b * LQ + t0 + r) * 32 + j] = xdbl[r * 40 + 4 + j];
  }
}

// ---------------- Mamba K3a: chunked scan phase 1 — per-chunk (P = prod a, f = local state)
// grid: b(16) x dg(8) x chunk(32) = 4096 blocks; 256 thr = 16 d_local x 16 j
__global__ void __launch_bounds__(256) k_scan_p1(const float* __restrict__ dtb,
    const float* __restrict__ xib, const float* __restrict__ bcb,
    const float* __restrict__ alog, float* __restrict__ Pb, float* __restrict__ fb) {
  __shared__ float sdt[CT * 16], sx[CT * 16], sbc[CT * 32];
  int blk = blockIdx.x;
  int c = blk & 31, dg = (blk >> 5) & 7, b = blk >> 8;
  int tid = threadIdx.x;
  int ln = tid & 63;
  int dl = (tid >> 6) * 4 + (ln >> 4);
  int j = ln & 15;
  int t0 = c * CT;
  size_t rowb = (size_t)(b * LQ + t0);
  for (int i = tid; i < CT * 4; i += 256) {
    int r = i >> 2, q = i & 3;
    ((float4*)sdt)[i] = *(const float4*)&dtb[(rowb + r) * DI + dg * 16 + q * 4];
    ((float4*)sx)[i]  = *(const float4*)&xib[(rowb + r) * DI + dg * 16 + q * 4];
  }
  for (int i = tid; i < CT * 8; i += 256) {
    int r = i >> 3, q = i & 7;
    ((float4*)sbc)[i] = *(const float4*)&bcb[(rowb + r) * 32 + q * 4];
  }
  float A2 = -__expf(alog[(dg * 16 + dl) * 16 + j]) * 1.4426950408889634f;
  __syncthreads();
  float P = 1.0f, s = 0.0f;
#pragma unroll 4
  for (int tt = 0; tt < CT; ++tt) {
    float dtv = sdt[tt * 16 + dl];
    float xv  = sx[tt * 16 + dl];
    float Bv  = sbc[tt * 32 + j];
    float a = exp2f(dtv * A2);
    P *= a;
    s = a * s + (dtv * xv) * Bv;
  }
  Pb[(size_t)blk * 256 + tid] = P;
  fb[(size_t)blk * 256 + tid] = s;
}

// ---------------- Mamba K3b: sequential combine over chunks -> chunk-start states
__global__ void __launch_bounds__(256) k_scan_p2(const float* __restrict__ Pb,
    const float* __restrict__ fb, float* __restrict__ Sb) {
  int idx = blockIdx.x * 256 + threadIdx.x;   // (b*8+dg)*256 + r
  int grp = idx >> 8, r = idx & 255;
  float s = 0.0f;
  for (int c = 0; c < NCH; ++c) {
    size_t a = ((size_t)grp * NCH + c) * 256 + r;
    Sb[a] = s;
    s = Pb[a] * s + fb[a];
  }
}

// ---------------- Mamba K3c: phase 3 — re-run recurrence from Sstart, emit y (in-place into dtb)
__global__ void __launch_bounds__(256) k_scan_p3(float* __restrict__ dtb,
    const float* __restrict__ xib, const float* __restrict__ bcb,
    const float* __restrict__ alog, const float* __restrict__ Sb) {
  __shared__ float sdt[CT * 16], sx[CT * 16], sbc[CT * 32];
  __shared__ float yt[CT * 16];
  int blk = blockIdx.x;
  int c = blk & 31, dg = (blk >> 5) & 7, b = blk >> 8;
  int tid = threadIdx.x;
  int ln = tid & 63;
  int dl = (tid >> 6) * 4 + (ln >> 4);
  int j = ln & 15;
  int t0 = c * CT;
  size_t rowb = (size_t)(b * LQ + t0);
  for (int i = tid; i < CT * 4; i += 256) {
    int r = i >> 2, q = i & 3;
    ((float4*)sdt)[i] = *(const float4*)&dtb[(rowb + r) * DI + dg * 16 + q * 4];
    ((float4*)sx)[i]  = *(const float4*)&xib[(rowb + r) * DI + dg * 16 + q * 4];
  }
  for (int i = tid; i < CT * 8; i += 256) {
    int r = i >> 3, q = i & 7;
    ((float4*)sbc)[i] = *(const float4*)&bcb[(rowb + r) * 32 + q * 4];
  }
  float A2 = -__expf(alog[(dg * 16 + dl) * 16 + j]) * 1.4426950408889634f;
  float s = Sb[(size_t)blk * 256 + tid];
  __syncthreads();
#pragma unroll 4
  for (int tt = 0; tt < CT; ++tt) {
    float dtv = sdt[tt * 16 + dl];
    float xv  = sx[tt * 16 + dl];
    float Bv  = sbc[tt * 32 + j];
    float Cv  = sbc[tt * 32 + 16 + j];
    float a = exp2f(dtv * A2);
    s = a * s + (dtv * xv) * Bv;
    float p = s * Cv;
    p += __shfl_xor(p, 1);
    p += __shfl_xor(p, 2);
    p += __shfl_xor(p, 4);
    p += __shfl_xor(p, 8);
    if (j == 0) yt[tt * 16 + dl] = p;
  }
  __syncthreads();
  for (int i = tid; i < CT * 4; i += 256) {
    int r = i >> 2, q = i & 3;
    *(float4*)&dtb[(rowb + r) * DI + dg * 16 + q * 4] = ((float4*)yt)[i];
  }
}

// ---------------- Mamba K4: y = ys + xi*Dp; gate with silu(z); out_proj (64x128); res +=
__global__ void __launch_bounds__(256) k_gate(const float* __restrict__ ys,
    const float* __restrict__ xib, const float* __restrict__ zb,
    const float* __restrict__ Dpl, const float* __restrict__ outw,
    float* __restrict__ res) {
  __shared__ float gt[64 * 128];
  __shared__ float4 w4[16 * 64];   // half the kb range per pass
  int tid = threadIdx.x;
  int b = blockIdx.x >> 5;
  int t0 = (blockIdx.x & 31) * 64;
  size_t base = (size_t)(b * LQ + t0) * DI;
  const float4* ys4 = (const float4*)(ys + base);
  const float4* xi4 = (const float4*)(xib + base);
  const float4* zb4 = (const float4*)(zb + base);
  const float4* dp4 = (const float4*)Dpl;
  for (int i = tid; i < 2048; i += 256) {
    float4 yv = ys4[i], xv = xi4[i], zv = zb4[i];
    float4 dp = dp4[i & 31];
    float4 o;
    o.x = (yv.x + xv.x * dp.x) * zv.x * sigmoidf_(zv.x);
    o.y = (yv.y + xv.y * dp.y) * zv.y * sigmoidf_(zv.y);
    o.z = (yv.z + xv.z * dp.z) * zv.z * sigmoidf_(zv.z);
    o.w = (yv.w + xv.w * dp.w) * zv.w * sigmoidf_(zv.w);
    *(float4*)&gt[i * 4] = o;
  }
  int wv = tid >> 6, lane = tid & 63;
  float acc[2][8];
#pragma unroll
  for (int rb = 0; rb < 2; ++rb)
#pragma unroll
    for (int rr = 0; rr < 8; ++rr) acc[rb][rr] = 0.0f;
  for (int h = 0; h < 2; ++h) {
    __syncthreads();
    for (int i = tid; i < 1024; i += 256) {
      int c = i >> 4, kb = i & 15;
      w4[kb * 64 + c] = ((const float4*)outw)[c * 32 + h * 16 + kb];
    }
    __syncthreads();
    for (int rb = 0; rb < 2; ++rb) {
      int r0 = wv * 16 + rb * 8;
      for (int kb = 0; kb < 16; ++kb) {
        float4 wvv = w4[kb * 64 + lane];
        int kk = (h * 16 + kb) * 4;
#pragma unroll
        for (int rr = 0; rr < 8; ++rr) {
          float4 xv = *(const float4*)&gt[(r0 + rr) * 128 + kk];
          acc[rb][rr] += wvv.x * xv.x + wvv.y * xv.y + wvv.z * xv.z + wvv.w * xv.w;
        }
      }
    }
  }
#pragma unroll
  for (int rb = 0; rb < 2; ++rb)
#pragma unroll
    for (int rr = 0; rr < 8; ++rr)
      res[(size_t)(b * LQ + t0 + wv * 16 + rb * 8 + rr) * 64 + lane] += acc[rb][rr];
}

// ---------------- Final LayerNorm: res -> hf, one wave per row
__global__ void __launch_bounds__(256) k_lnfinal(const float* __restrict__ res,
    const float* __restrict__ g, const float* __restrict__ bb, float* __restrict__ hf) {
  int row = blockIdx.x * 4 + (threadIdx.x >> 6);
  int lane = threadIdx.x & 63;
  float v = res[row * 64 + lane];
  float s = v;
#pragma unroll
  for (int m = 32; m >= 1; m >>= 1) s += __shfl_xor(s, m);
  float mean = s * (1.0f / 64.0f);
  float dd = v - mean;
  float q = dd * dd;
#pragma unroll
  for (int m = 32; m >= 1; m >>= 1) q += __shfl_xor(q, m);
  float iv = rsqrtf(q * (1.0f / 64.0f) + EPS);
  hf[row * 64 + lane] = dd * iv * g[lane] + bb[lane];
}

// ---------------- Classifier conv: 64->64 K=5 stride2 pad2 + BN + ReLU
__global__ void __launch_bounds__(256) k_cls(const float* __restrict__ in,
    float* __restrict__ out, const float* __restrict__ w,
    const float* __restrict__ bb, const float* __restrict__ g,
    const float* __restrict__ be, int Lin, int Lout, int layout) {
  __shared__ float xin[64 * 136];   // 64 ci x 131 (span), padded
  __shared__ float wl[16 * 320];    // 16 out-ch per pass
  int tid = threadIdx.x;
  int tilesPerB = Lout >> 6;
  int b = blockIdx.x / tilesPerB;
  int t0 = (blockIdx.x % tilesPerB) * 64;
  int lbase = 2 * t0 - 2;
  if (layout == 0) {
    for (int i = tid; i < 64 * 131; i += 256) {
      int lr = i >> 6, ci = i & 63;
      int l = lbase + lr;
      xin[ci * 136 + lr] = (l >= 0 && l < Lin) ? in[(b * Lin + l) * 64 + ci] : 0.0f;
    }
  } else {
    for (int i = tid; i < 64 * 132; i += 256) {
      int ci = i / 132, lr = i % 132;
      if (lr < 131) {
        int l = lbase + lr;
        xin[ci * 136 + lr] = (l >= 0 && l < Lin) ? in[(b * 64 + ci) * Lin + l] : 0.0f;
      }
    }
  }
  int wv = tid >> 6, lane = tid & 63;
  float rs = rsqrtf(1.0f + EPS);
  for (int p = 0; p < 4; ++p) {
    __syncthreads();
    for (int i = tid; i < 16 * 320; i += 256) wl[i] = w[p * 16 * 320 + i];
    __syncthreads();
    float acc[4] = {0.0f, 0.0f, 0.0f, 0.0f};
    for (int ci = 0; ci < 64; ++ci) {
      const float* xr = &xin[ci * 136 + 2 * lane];
      float v0 = xr[0], v1 = xr[1], v2 = xr[2], v3 = xr[3], v4 = xr[4];
      const float* wr = &wl[(wv * 4) * 320 + ci * 5];
#pragma unroll
      for (int i2 = 0; i2 < 4; ++i2) {
        acc[i2] += wr[i2 * 320 + 0] * v0 + wr[i2 * 320 + 1] * v1 + wr[i2 * 320 + 2] * v2
                 + wr[i2 * 320 + 3] * v3 + wr[i2 * 320 + 4] * v4;
      }
    }
#pragma unroll
    for (int i2 = 0; i2 < 4; ++i2) {
      int co = p * 16 + wv * 4 + i2;
      float v = (acc[i2] + bb[co]) * (g[co] * rs) + be[co];
      out[(b * 64 + co) * Lout + t0 + lane] = fmaxf(v, 0.0f);
    }
  }
}

// ---------------- fc1 weight transpose prep
__global__ void __launch_bounds__(256) k_prep_fc1(const float* __restrict__ w,
                                                  float* __restrict__ wt) {
  int i = blockIdx.x * 256 + threadIdx.x;   // i < 131072
  int kb = i >> 8, f = i & 255;
  ((float4*)wt)[i] = ((const float4*)w)[f * 512 + kb];
}

// ---------------- Pool + FC1 + BN + ReLU + FC2
__global__ void __launch_bounds__(256) k_fc(const float* __restrict__ cin,
    const float* __restrict__ w1t, const float* __restrict__ b1,
    const float* __restrict__ g, const float* __restrict__ be,
    const float* __restrict__ w2, const float* __restrict__ b2,
    float* __restrict__ dout) {
  __shared__ float pooled[2048];
  __shared__ float feat[256];
  int tid = threadIdx.x;
  int b = blockIdx.x;
  for (int i = tid; i < 2048; i += 256) {
    float4 v = ((const float4*)cin)[b * 2048 + i];
    pooled[i] = (v.x + v.y + v.z + v.w) * 0.25f;
  }
  __syncthreads();
  float acc = b1[tid];
  const float4* wt4 = (const float4*)w1t;
  for (int kb = 0; kb < 512; ++kb) {
    float4 wv = wt4[kb * 256 + tid];
    float4 pv = *(const float4*)&pooled[kb * 4];
    acc += wv.x * pv.x + wv.y * pv.y + wv.z * pv.z + wv.w * pv.w;
  }
  float v = acc * (g[tid] * rsqrtf(1.0f + EPS)) + be[tid];
  feat[tid] = fmaxf(v, 0.0f);
  __syncthreads();
  if (tid < 5) {
    float a2 = b2[tid];
    for (int k = 0; k < 256; ++k) a2 += w2[tid * 256 + k] * feat[k];
    dout[b * 5 + tid] = a2;
  }
}

extern "C" void kernel_launch(void* const* d_in, const int* in_sizes, int n_in,
                              void* d_out, int out_size, void* d_ws, size_t ws_size,
                              hipStream_t stream) {
  (void)in_sizes; (void)n_in; (void)out_size; (void)ws_size;
  const float* x      = (const float*)d_in[0];
  const float* dw1    = (const float*)d_in[1];
  const float* db1    = (const float*)d_in[2];
  const float* dg1    = (const float*)d_in[3];
  const float* dbe1   = (const float*)d_in[4];
  const float* dw2    = (const float*)d_in[5];
  const float* db2    = (const float*)d_in[6];
  const float* dg2    = (const float*)d_in[7];
  const float* dbe2   = (const float*)d_in[8];
  const float* lng    = (const float*)d_in[9];
  const float* lnb    = (const float*)d_in[10];
  const float* inw    = (const float*)d_in[11];
  const float* convw  = (const float*)d_in[12];
  const float* convb  = (const float*)d_in[13];
  const float* xprojw = (const float*)d_in[14];
  const float* dtpw   = (const float*)d_in[15];
  const float* dtpb   = (const float*)d_in[16];
  const float* alog   = (const float*)d_in[17];
  const float* Dp     = (const float*)d_in[18];
  const float* outw   = (const float*)d_in[19];
  const float* flng   = (const float*)d_in[20];
  const float* flnb   = (const float*)d_in[21];
  const float* clsw1  = (const float*)d_in[22];
  const float* clsb1  = (const float*)d_in[23];
  const float* clsg1  = (const float*)d_in[24];
  const float* clsbe1 = (const float*)d_in[25];
  const float* clswR  = (const float*)d_in[26];
  const float* clsbR  = (const float*)d_in[27];
  const float* clsgR  = (const float*)d_in[28];
  const float* clsbeR = (const float*)d_in[29];
  const float* fc1w   = (const float*)d_in[30];
  const float* fc1b   = (const float*)d_in[31];
  const float* fcg    = (const float*)d_in[32];
  const float* fcbe   = (const float*)d_in[33];
  const float* fc2w   = (const float*)d_in[34];
  const float* fc2b   = (const float*)d_in[35];

  float* ws = (float*)d_ws;
  float* h1    = ws;                    // 2,097,152  (B,64,L); reused as hf later
  float* res   = ws + 2097152;          // 2,097,152  (B,L,64)
  float* xiraw = ws + 4194304;          // 4,194,304  (B,L,128)
  float* zb    = ws + 8388608;          // 4,194,304
  float* xib   = ws + 12582912;         // 4,194,304
  float* dtb   = ws + 16777216;         // 4,194,304  (dt, overwritten by ys in scan)
  float* bcb   = ws + 20971520;         // 1,048,576  (B,L,32)
  float* fc1t  = ws + 22020096;         // 524,288
  // scan temp buffers reuse xiraw region (free during scan phase)
  float* Pb = xiraw;                    // 1,048,576
  float* fb = xiraw + 1048576;          // 1,048,576
  float* Sb = xiraw + 2097152;          // 1,048,576
  // classifier buffers reuse xiraw region (free after mamba layers)
  float* c1 = xiraw;
  float* c2 = xiraw + 1048576;
  float* c3 = xiraw + 1572864;
  float* c4 = xiraw + 1835008;
  float* hf = h1;

  k_prep_fc1<<<512, 256, 0, stream>>>(fc1w, fc1t);
  k_front<<<8192, 256, 0, stream>>>(x, dw1, db1, dg1, dbe1, h1);
  k_conv2<<<512, 256, 0, stream>>>(h1, dw2, db2, dg2, dbe2, res);
  for (int il = 0; il < 4; ++il) {
    k_lnproj<<<512, 256, 0, stream>>>(res, lng + il * 64, lnb + il * 64,
                                      inw + il * 16384, xiraw, zb);
    k_convx<<<1024, 256, 0, stream>>>(xiraw, convw + il * 512, convb + il * 128,
                                      xprojw + il * 4608, dtpw + il * 512,
                                      dtpb + il * 128, xib, dtb, bcb);
    k_scan_p1<<<4096, 256, 0, stream>>>(dtb, xib, bcb, alog + il * 2048, Pb, fb);
    k_scan_p2<<<128, 256, 0, stream>>>(Pb, fb, Sb);
    k_scan_p3<<<4096, 256, 0, stream>>>(dtb, xib, bcb, alog + il * 2048, Sb);
    k_gate<<<512, 256, 0, stream>>>(dtb, xib, zb, Dp + il * 128,
                                    outw + il * 8192, res);
  }
  k_lnfinal<<<8192, 256, 0, stream>>>(res, flng, flnb, hf);
  k_cls<<<256, 256, 0, stream>>>(hf, c1, clsw1, clsb1, clsg1, clsbe1, 2048, 1024, 0);
  k_cls<<<128, 256, 0, stream>>>(c1, c2, clswR + 0 * 20480, clsbR + 0, clsgR + 0,
                                 clsbeR + 0, 1024, 512, 1);
  k_cls<<<64, 256, 0, stream>>>(c2, c3, clswR + 1 * 20480, clsbR + 64, clsgR + 64,
                                clsbeR + 64, 512, 256, 1);
  k_cls<<<32, 256, 0, stream>>>(c3, c4, clswR + 2 * 20480, clsbR + 128, clsgR + 128,
                                clsbeR + 128, 256, 128, 1);
  k_fc<<<16, 256, 0, stream>>>(c4, fc1t, fc1b, fcg, fcbe, fc2w, fc2b, (float*)d_out);
}

// Round 3
// 1379.944 us; speedup vs baseline: 3.8744x; 1.5198x over previous
//
#include <hip/hip_runtime.h>

#define DINL static __device__ __forceinline__

namespace {
constexpr int BN = 16;
constexpr int LQ = 2048;
constexpr int DM = 64;
constexpr int DI = 128;
constexpr float EPS = 1e-5f;
constexpr int NCH = 32;   // scan chunks
constexpr int CT = 64;    // chunk length (NCH*CT == LQ)
}

DINL float sigmoidf_(float x) { return 1.0f / (1.0f + __expf(-x)); }

// ---------------- Stage A: conv1d 1->64 K=3 pad1 + BN + ReLU -> h1 (B,64,L)
__global__ void __launch_bounds__(256) k_front(const float* __restrict__ x,
    const float* __restrict__ w, const float* __restrict__ bb,
    const float* __restrict__ g, const float* __restrict__ be,
    float* __restrict__ h1) {
  int idx = blockIdx.x * 256 + threadIdx.x;   // (b*64+c)*2048 + l
  int l = idx & (LQ - 1);
  int c = (idx >> 11) & 63;
  int b = idx >> 17;
  const float* xr = x + b * LQ;
  float xm = (l > 0) ? xr[l - 1] : 0.0f;
  float x0 = xr[l];
  float xp = (l < LQ - 1) ? xr[l + 1] : 0.0f;
  float acc = w[c * 3 + 0] * xm + w[c * 3 + 1] * x0 + w[c * 3 + 2] * xp + bb[c];
  float v = acc * (g[c] * rsqrtf(1.0f + EPS)) + be[c];
  h1[idx] = fmaxf(v, 0.0f);
}

// ---------------- Stage B: conv1d 64->64 K=3 pad1 + BN + ReLU, write transposed res (B,L,64)
__global__ void __launch_bounds__(256) k_conv2(const float* __restrict__ h1,
    const float* __restrict__ w, const float* __restrict__ bb,
    const float* __restrict__ g, const float* __restrict__ be,
    float* __restrict__ res) {
  __shared__ float xin[64 * 66];   // 64 ci x (64+2)
  __shared__ float wl[32 * 192];   // half the out channels per pass
  __shared__ float os[64 * 65];    // out staging (l, c) padded
  int tid = threadIdx.x;
  int b = blockIdx.x >> 5;
  int t0 = (blockIdx.x & 31) * 64;
  for (int i = tid; i < 64 * 66; i += 256) {
    int ci = i / 66, j = i % 66;
    int l = t0 - 1 + j;
    xin[i] = (l >= 0 && l < LQ) ? h1[(b * 64 + ci) * LQ + l] : 0.0f;
  }
  int wv = tid >> 6, lane = tid & 63;
  float rs = rsqrtf(1.0f + EPS);
  for (int p = 0; p < 2; ++p) {
    __syncthreads();
    for (int i = tid; i < 32 * 192; i += 256) wl[i] = w[p * 32 * 192 + i];
    __syncthreads();
    float acc[8];
#pragma unroll
    for (int i2 = 0; i2 < 8; ++i2) acc[i2] = 0.0f;
    for (int ci = 0; ci < 64; ++ci) {
      float x0 = xin[ci * 66 + lane];
      float x1 = xin[ci * 66 + lane + 1];
      float x2 = xin[ci * 66 + lane + 2];
      const float* wr = &wl[(wv * 8) * 192 + ci * 3];
#pragma unroll
      for (int i2 = 0; i2 < 8; ++i2)
        acc[i2] += wr[i2 * 192 + 0] * x0 + wr[i2 * 192 + 1] * x1 + wr[i2 * 192 + 2] * x2;
    }
#pragma unroll
    for (int i2 = 0; i2 < 8; ++i2) {
      int co = p * 32 + wv * 8 + i2;
      float v = (acc[i2] + bb[co]) * (g[co] * rs) + be[co];
      os[lane * 65 + co] = fmaxf(v, 0.0f);
    }
  }
  __syncthreads();
  for (int i = tid; i < 4096; i += 256) {
    int r = i >> 6, c = i & 63;
    res[(b * LQ + t0 + r) * 64 + c] = os[r * 65 + c];
  }
}

// ---------------- Mamba K1: LayerNorm + in_proj (256x64), split to xi_raw / z
__global__ void __launch_bounds__(256) k_lnproj(const float* __restrict__ res,
    const float* __restrict__ lng, const float* __restrict__ lnb,
    const float* __restrict__ inw, float* __restrict__ xiraw, float* __restrict__ zb) {
  __shared__ float tile[64 * 68];     // rows padded to 68 (16B aligned)
  __shared__ float4 w4[16 * 128];     // w4[kb*128 + c] : contiguous per-lane reads
  __shared__ float gl[64], bl[64], mA[64], ivA[64];
  int tid = threadIdx.x;
  int b = blockIdx.x >> 5;
  int t0 = (blockIdx.x & 31) * 64;
  const float* rb0 = res + (size_t)(b * LQ + t0) * 64;
  for (int i = tid; i < 1024; i += 256) {
    int r = i >> 4, kb = i & 15;
    *(float4*)&tile[r * 68 + kb * 4] = ((const float4*)rb0)[i];
  }
  if (tid < 64) gl[tid] = lng[tid];
  else if (tid < 128) bl[tid - 64] = lnb[tid - 64];
  __syncthreads();
  if (tid < 64) {
    float s = 0.0f;
#pragma unroll
    for (int k = 0; k < 64; ++k) s += tile[tid * 68 + k];
    float m = s * (1.0f / 64.0f);
    float q = 0.0f;
#pragma unroll
    for (int k = 0; k < 64; ++k) { float dd = tile[tid * 68 + k] - m; q += dd * dd; }
    mA[tid] = m;
    ivA[tid] = rsqrtf(q * (1.0f / 64.0f) + EPS);
  }
  __syncthreads();
  for (int i = tid; i < 4096; i += 256) {
    int r = i >> 6, k = i & 63;
    tile[r * 68 + k] = (tile[r * 68 + k] - mA[r]) * ivA[r] * gl[k] + bl[k];
  }
  int wv = tid >> 6, lane = tid & 63;
  const float4* wsrc = (const float4*)inw;
  for (int p = 0; p < 2; ++p) {
    __syncthreads();
    for (int i = tid; i < 2048; i += 256) {
      int c = i >> 4, kb = i & 15;
      w4[kb * 128 + c] = wsrc[p * 2048 + i];
    }
    __syncthreads();
    float* outp = (p == 0) ? xiraw : zb;
    for (int ci = 0; ci < 2; ++ci) {
      int c = ci * 64 + lane;
      for (int rbk = 0; rbk < 2; ++rbk) {
        int r0 = wv * 16 + rbk * 8;
        float acc[8];
#pragma unroll
        for (int rr = 0; rr < 8; ++rr) acc[rr] = 0.0f;
        for (int kb = 0; kb < 16; ++kb) {
          float4 wvv = w4[kb * 128 + c];
#pragma unroll
          for (int rr = 0; rr < 8; ++rr) {
            float4 xv = *(const float4*)&tile[(r0 + rr) * 68 + kb * 4];
            acc[rr] += wvv.x * xv.x + wvv.y * xv.y + wvv.z * xv.z + wvv.w * xv.w;
          }
        }
#pragma unroll
        for (int rr = 0; rr < 8; ++rr)
          outp[(size_t)(b * LQ + t0 + r0 + rr) * DI + c] = acc[rr];
      }
    }
  }
}

// ---------------- Mamba K2: causal depthwise conv K=4 + SiLU + x_proj + dt_proj(softplus)
__global__ void __launch_bounds__(256) k_convx(const float* __restrict__ xiraw,
    const float* __restrict__ cw, const float* __restrict__ cb,
    const float* __restrict__ xw, const float* __restrict__ dtw,
    const float* __restrict__ dtbias, float* __restrict__ xib,
    float* __restrict__ dtb, float* __restrict__ bcb) {
  __shared__ float xin[35 * 128];
  __shared__ float xit[32 * 128];
  __shared__ float4 xw4[32 * 36];   // xw4[kb*36 + c]
  __shared__ float xdbl[32 * 40];
  __shared__ float4 cw4[128];
  __shared__ float cbl[128];
  __shared__ float4 dtw4[128];
  __shared__ float dtbl[128];
  int tid = threadIdx.x;
  int b = blockIdx.x >> 6;
  int t0 = (blockIdx.x & 63) * 32;
  for (int i = tid; i < 1120; i += 256) {     // 35*128/4 float4 loads
    int r = i >> 5, dq = i & 31;
    int l = t0 - 3 + r;
    float4 v = make_float4(0.f, 0.f, 0.f, 0.f);
    if (l >= 0) v = ((const float4*)xiraw)[(size_t)(b * LQ + l) * 32 + dq];
    *(float4*)&xin[r * 128 + dq * 4] = v;
  }
  if (tid < 128) {
    cw4[tid] = ((const float4*)cw)[tid];
    cbl[tid] = cb[tid];
    dtw4[tid] = ((const float4*)dtw)[tid];
    dtbl[tid] = dtbias[tid];
  }
  for (int i = tid; i < 32 * 36; i += 256) {
    xw4[(i & 31) * 36 + (i >> 5)] = ((const float4*)xw)[i];
  }
  __syncthreads();
  for (int i = tid; i < 32 * 128; i += 256) {
    int r = i >> 7, d = i & 127;
    float4 cv = cw4[d];
    float a = cbl[d] + cv.x * xin[r * 128 + d] + cv.y * xin[(r + 1) * 128 + d]
            + cv.z * xin[(r + 2) * 128 + d] + cv.w * xin[(r + 3) * 128 + d];
    float v = a * sigmoidf_(a);
    xit[i] = v;
    xib[(size_t)(b * LQ + t0 + r) * DI + d] = v;
  }
  __syncthreads();
  int wv = tid >> 6, lane = tid & 63;
  if (lane < 36) {
    int r0 = wv * 8;
    float acc[8];
#pragma unroll
    for (int rr = 0; rr < 8; ++rr) acc[rr] = 0.0f;
    for (int kb = 0; kb < 32; ++kb) {
      float4 wvv = xw4[kb * 36 + lane];
#pragma unroll
      for (int rr = 0; rr < 8; ++rr) {
        float4 xv = *(const float4*)&xit[(r0 + rr) * 128 + kb * 4];
        acc[rr] += wvv.x * xv.x + wvv.y * xv.y + wvv.z * xv.z + wvv.w * xv.w;
      }
    }
#pragma unroll
    for (int rr = 0; rr < 8; ++rr) xdbl[(r0 + rr) * 40 + lane] = acc[rr];
  }
  __syncthreads();
  for (int i = tid; i < 32 * 128; i += 256) {
    int r = i >> 7, d = i & 127;
    float4 wvv = dtw4[d];
    float4 xd = *(const float4*)&xdbl[r * 40];
    float sv = dtbl[d] + wvv.x * xd.x + wvv.y * xd.y + wvv.z * xd.z + wvv.w * xd.w;
    dtb[(size_t)(b * LQ + t0 + r) * DI + d] = (sv > 20.0f) ? sv : log1pf(__expf(sv));
  }
  for (int i = tid; i < 32 * 32; i += 256) {
    int r = i >> 5, j = i & 31;
    bcb[(size_t)(b * LQ + t0 + r) * 32 + j] = xdbl[r * 40 + 4 + j];
  }
}

// ---------------- Mamba K3a: chunked scan phase 1 — per-chunk (P = prod a, f = local state)
__global__ void __launch_bounds__(256) k_scan_p1(const float* __restrict__ dtb,
    const float* __restrict__ xib, const float* __restrict__ bcb,
    const float* __restrict__ alog, float* __restrict__ Pb, float* __restrict__ fb) {
  __shared__ float sdt[CT * 16], sx[CT * 16], sbc[CT * 32];
  int blk = blockIdx.x;
  int c = blk & 31, dg = (blk >> 5) & 7, b = blk >> 8;
  int tid = threadIdx.x;
  int ln = tid & 63;
  int dl = (tid >> 6) * 4 + (ln >> 4);
  int j = ln & 15;
  int t0 = c * CT;
  size_t rowb = (size_t)(b * LQ + t0);
  for (int i = tid; i < CT * 4; i += 256) {
    int r = i >> 2, q = i & 3;
    ((float4*)sdt)[i] = *(const float4*)&dtb[(rowb + r) * DI + dg * 16 + q * 4];
    ((float4*)sx)[i]  = *(const float4*)&xib[(rowb + r) * DI + dg * 16 + q * 4];
  }
  for (int i = tid; i < CT * 8; i += 256) {
    int r = i >> 3, q = i & 7;
    ((float4*)sbc)[i] = *(const float4*)&bcb[(rowb + r) * 32 + q * 4];
  }
  float A2 = -__expf(alog[(dg * 16 + dl) * 16 + j]) * 1.4426950408889634f;
  __syncthreads();
  float P = 1.0f, s = 0.0f;
#pragma unroll 4
  for (int tt = 0; tt < CT; ++tt) {
    float dtv = sdt[tt * 16 + dl];
    float xv  = sx[tt * 16 + dl];
    float Bv  = sbc[tt * 32 + j];
    float a = exp2f(dtv * A2);
    P *= a;
    s = a * s + (dtv * xv) * Bv;
  }
  Pb[(size_t)blk * 256 + tid] = P;
  fb[(size_t)blk * 256 + tid] = s;
}

// ---------------- Mamba K3b: sequential combine over chunks -> chunk-start states
__global__ void __launch_bounds__(256) k_scan_p2(const float* __restrict__ Pb,
    const float* __restrict__ fb, float* __restrict__ Sb) {
  int idx = blockIdx.x * 256 + threadIdx.x;   // (b*8+dg)*256 + r
  int grp = idx >> 8, r = idx & 255;
  float s = 0.0f;
  for (int c = 0; c < NCH; ++c) {
    size_t a = ((size_t)grp * NCH + c) * 256 + r;
    Sb[a] = s;
    s = Pb[a] * s + fb[a];
  }
}

// ---------------- Mamba K3c: re-run recurrence from Sstart; emit GATED y in-place into dtb:
// y = (scan_out + xi*Dp) * silu(z)
__global__ void __launch_bounds__(256) k_scan_p3(float* __restrict__ dtb,
    const float* __restrict__ xib, const float* __restrict__ bcb,
    const float* __restrict__ zb, const float* __restrict__ Dpl,
    const float* __restrict__ alog, const float* __restrict__ Sb) {
  __shared__ float sdt[CT * 16], sx[CT * 16], sbc[CT * 32], sz[CT * 16];
  __shared__ float yt[CT * 16];
  int blk = blockIdx.x;
  int c = blk & 31, dg = (blk >> 5) & 7, b = blk >> 8;
  int tid = threadIdx.x;
  int ln = tid & 63;
  int dl = (tid >> 6) * 4 + (ln >> 4);
  int j = ln & 15;
  int t0 = c * CT;
  size_t rowb = (size_t)(b * LQ + t0);
  for (int i = tid; i < CT * 4; i += 256) {
    int r = i >> 2, q = i & 3;
    ((float4*)sdt)[i] = *(const float4*)&dtb[(rowb + r) * DI + dg * 16 + q * 4];
    ((float4*)sx)[i]  = *(const float4*)&xib[(rowb + r) * DI + dg * 16 + q * 4];
    ((float4*)sz)[i]  = *(const float4*)&zb[(rowb + r) * DI + dg * 16 + q * 4];
  }
  for (int i = tid; i < CT * 8; i += 256) {
    int r = i >> 3, q = i & 7;
    ((float4*)sbc)[i] = *(const float4*)&bcb[(rowb + r) * 32 + q * 4];
  }
  float A2 = -__expf(alog[(dg * 16 + dl) * 16 + j]) * 1.4426950408889634f;
  float Dv = Dpl[dg * 16 + dl];
  float s = Sb[(size_t)blk * 256 + tid];
  __syncthreads();
#pragma unroll 4
  for (int tt = 0; tt < CT; ++tt) {
    float dtv = sdt[tt * 16 + dl];
    float xv  = sx[tt * 16 + dl];
    float Bv  = sbc[tt * 32 + j];
    float Cv  = sbc[tt * 32 + 16 + j];
    float a = exp2f(dtv * A2);
    s = a * s + (dtv * xv) * Bv;
    float p = s * Cv;
    p += __shfl_xor(p, 1);
    p += __shfl_xor(p, 2);
    p += __shfl_xor(p, 4);
    p += __shfl_xor(p, 8);
    if (j == 0) {
      float zv = sz[tt * 16 + dl];
      yt[tt * 16 + dl] = (p + xv * Dv) * zv * sigmoidf_(zv);
    }
  }
  __syncthreads();
  for (int i = tid; i < CT * 4; i += 256) {
    int r = i >> 2, q = i & 3;
    *(float4*)&dtb[(rowb + r) * DI + dg * 16 + q * 4] = ((float4*)yt)[i];
  }
}

// ---------------- Mamba K4: out_proj (64 out x 128 k) on gated activations; res +=
__global__ void __launch_bounds__(256, 2) k_outproj(const float* __restrict__ gt_g,
    const float* __restrict__ outw, float* __restrict__ res) {
  __shared__ float gt[64 * 128];
  __shared__ float4 w4s[32 * 64];   // w4s[kb*64 + (c+kb)&63] (swizzled, conflict-free stage)
  int tid = threadIdx.x;
  int b = blockIdx.x >> 5;
  int t0 = (blockIdx.x & 31) * 64;
  size_t base = (size_t)(b * LQ + t0) * DI;
  const float4* src4 = (const float4*)(gt_g + base);
  for (int i = tid; i < 2048; i += 256)
    ((float4*)gt)[i] = src4[i];
  for (int i = tid; i < 2048; i += 256) {
    int c = i >> 5, kb = i & 31;
    w4s[kb * 64 + ((c + kb) & 63)] = ((const float4*)outw)[i];
  }
  __syncthreads();
  int wv = tid >> 6, lane = tid & 63;
  int r0 = wv * 16;
  float acc[16];
#pragma unroll
  for (int rr = 0; rr < 16; ++rr) acc[rr] = 0.0f;
#pragma unroll 2
  for (int kb = 0; kb < 32; ++kb) {
    float4 wvv = w4s[kb * 64 + ((lane + kb) & 63)];
#pragma unroll
    for (int rr = 0; rr < 16; ++rr) {
      float4 xv = *(const float4*)&gt[(r0 + rr) * 128 + kb * 4];
      acc[rr] += wvv.x * xv.x + wvv.y * xv.y + wvv.z * xv.z + wvv.w * xv.w;
    }
  }
#pragma unroll
  for (int rr = 0; rr < 16; ++rr)
    res[(size_t)(b * LQ + t0 + r0 + rr) * 64 + lane] += acc[rr];
}

// ---------------- Final LayerNorm: res -> hf, one wave per row
__global__ void __launch_bounds__(256) k_lnfinal(const float* __restrict__ res,
    const float* __restrict__ g, const float* __restrict__ bb, float* __restrict__ hf) {
  int row = blockIdx.x * 4 + (threadIdx.x >> 6);
  int lane = threadIdx.x & 63;
  float v = res[row * 64 + lane];
  float s = v;
#pragma unroll
  for (int m = 32; m >= 1; m >>= 1) s += __shfl_xor(s, m);
  float mean = s * (1.0f / 64.0f);
  float dd = v - mean;
  float q = dd * dd;
#pragma unroll
  for (int m = 32; m >= 1; m >>= 1) q += __shfl_xor(q, m);
  float iv = rsqrtf(q * (1.0f / 64.0f) + EPS);
  hf[row * 64 + lane] = dd * iv * g[lane] + bb[lane];
}

// ---------------- Classifier conv: 64->64 K=5 stride2 pad2 + BN + ReLU
__global__ void __launch_bounds__(256) k_cls(const float* __restrict__ in,
    float* __restrict__ out, const float* __restrict__ w,
    const float* __restrict__ bb, const float* __restrict__ g,
    const float* __restrict__ be, int Lin, int Lout, int layout) {
  __shared__ float xin[64 * 136];   // 64 ci x 131 (span), padded
  __shared__ float wl[16 * 320];    // 16 out-ch per pass
  int tid = threadIdx.x;
  int tilesPerB = Lout >> 6;
  int b = blockIdx.x / tilesPerB;
  int t0 = (blockIdx.x % tilesPerB) * 64;
  int lbase = 2 * t0 - 2;
  if (layout == 0) {
    for (int i = tid; i < 64 * 131; i += 256) {
      int lr = i >> 6, ci = i & 63;
      int l = lbase + lr;
      xin[ci * 136 + lr] = (l >= 0 && l < Lin) ? in[(b * Lin + l) * 64 + ci] : 0.0f;
    }
  } else {
    for (int i = tid; i < 64 * 132; i += 256) {
      int ci = i / 132, lr = i % 132;
      if (lr < 131) {
        int l = lbase + lr;
        xin[ci * 136 + lr] = (l >= 0 && l < Lin) ? in[(b * 64 + ci) * Lin + l] : 0.0f;
      }
    }
  }
  int wv = tid >> 6, lane = tid & 63;
  float rs = rsqrtf(1.0f + EPS);
  for (int p = 0; p < 4; ++p) {
    __syncthreads();
    for (int i = tid; i < 16 * 320; i += 256) wl[i] = w[p * 16 * 320 + i];
    __syncthreads();
    float acc[4] = {0.0f, 0.0f, 0.0f, 0.0f};
    for (int ci = 0; ci < 64; ++ci) {
      const float* xr = &xin[ci * 136 + 2 * lane];
      float v0 = xr[0], v1 = xr[1], v2 = xr[2], v3 = xr[3], v4 = xr[4];
      const float* wr = &wl[(wv * 4) * 320 + ci * 5];
#pragma unroll
      for (int i2 = 0; i2 < 4; ++i2) {
        acc[i2] += wr[i2 * 320 + 0] * v0 + wr[i2 * 320 + 1] * v1 + wr[i2 * 320 + 2] * v2
                 + wr[i2 * 320 + 3] * v3 + wr[i2 * 320 + 4] * v4;
      }
    }
#pragma unroll
    for (int i2 = 0; i2 < 4; ++i2) {
      int co = p * 16 + wv * 4 + i2;
      float v = (acc[i2] + bb[co]) * (g[co] * rs) + be[co];
      out[(b * 64 + co) * Lout + t0 + lane] = fmaxf(v, 0.0f);
    }
  }
}

// ---------------- fc1 weight transpose prep
__global__ void __launch_bounds__(256) k_prep_fc1(const float* __restrict__ w,
                                                  float* __restrict__ wt) {
  int i = blockIdx.x * 256 + threadIdx.x;   // i < 131072
  int kb = i >> 8, f = i & 255;
  ((float4*)wt)[i] = ((const float4*)w)[f * 512 + kb];
}

// ---------------- Pool + FC1 + BN + ReLU + FC2
__global__ void __launch_bounds__(256) k_fc(const float* __restrict__ cin,
    const float* __restrict__ w1t, const float* __restrict__ b1,
    const float* __restrict__ g, const float* __restrict__ be,
    const float* __restrict__ w2, const float* __restrict__ b2,
    float* __restrict__ dout) {
  __shared__ float pooled[2048];
  __shared__ float feat[256];
  int tid = threadIdx.x;
  int b = blockIdx.x;
  for (int i = tid; i < 2048; i += 256) {
    float4 v = ((const float4*)cin)[b * 2048 + i];
    pooled[i] = (v.x + v.y + v.z + v.w) * 0.25f;
  }
  __syncthreads();
  float acc = b1[tid];
  const float4* wt4 = (const float4*)w1t;
  for (int kb = 0; kb < 512; ++kb) {
    float4 wv = wt4[kb * 256 + tid];
    float4 pv = *(const float4*)&pooled[kb * 4];
    acc += wv.x * pv.x + wv.y * pv.y + wv.z * pv.z + wv.w * pv.w;
  }
  float v = acc * (g[tid] * rsqrtf(1.0f + EPS)) + be[tid];
  feat[tid] = fmaxf(v, 0.0f);
  __syncthreads();
  if (tid < 5) {
    float a2 = b2[tid];
    for (int k = 0; k < 256; ++k) a2 += w2[tid * 256 + k] * feat[k];
    dout[b * 5 + tid] = a2;
  }
}

extern "C" void kernel_launch(void* const* d_in, const int* in_sizes, int n_in,
                              void* d_out, int out_size, void* d_ws, size_t ws_size,
                              hipStream_t stream) {
  (void)in_sizes; (void)n_in; (void)out_size; (void)ws_size;
  const float* x      = (const float*)d_in[0];
  const float* dw1    = (const float*)d_in[1];
  const float* db1    = (const float*)d_in[2];
  const float* dg1    = (const float*)d_in[3];
  const float* dbe1   = (const float*)d_in[4];
  const float* dw2    = (const float*)d_in[5];
  const float* db2    = (const float*)d_in[6];
  const float* dg2    = (const float*)d_in[7];
  const float* dbe2   = (const float*)d_in[8];
  const float* lng    = (const float*)d_in[9];
  const float* lnb    = (const float*)d_in[10];
  const float* inw    = (const float*)d_in[11];
  const float* convw  = (const float*)d_in[12];
  const float* convb  = (const float*)d_in[13];
  const float* xprojw = (const float*)d_in[14];
  const float* dtpw   = (const float*)d_in[15];
  const float* dtpb   = (const float*)d_in[16];
  const float* alog   = (const float*)d_in[17];
  const float* Dp     = (const float*)d_in[18];
  const float* outw   = (const float*)d_in[19];
  const float* flng   = (const float*)d_in[20];
  const float* flnb   = (const float*)d_in[21];
  const float* clsw1  = (const float*)d_in[22];
  const float* clsb1  = (const float*)d_in[23];
  const float* clsg1  = (const float*)d_in[24];
  const float* clsbe1 = (const float*)d_in[25];
  const float* clswR  = (const float*)d_in[26];
  const float* clsbR  = (const float*)d_in[27];
  const float* clsgR  = (const float*)d_in[28];
  const float* clsbeR = (const float*)d_in[29];
  const float* fc1w   = (const float*)d_in[30];
  const float* fc1b   = (const float*)d_in[31];
  const float* fcg    = (const float*)d_in[32];
  const float* fcbe   = (const float*)d_in[33];
  const float* fc2w   = (const float*)d_in[34];
  const float* fc2b   = (const float*)d_in[35];

  float* ws = (float*)d_ws;
  float* h1    = ws;                    // (B,64,L); reused as hf later
  float* res   = ws + 2097152;          // (B,L,64)
  float* xiraw = ws + 4194304;          // (B,L,128)
  float* zb    = ws + 8388608;
  float* xib   = ws + 12582912;
  float* dtb   = ws + 16777216;         // dt -> gated y (in-place through scan)
  float* bcb   = ws + 20971520;         // (B,L,32)
  float* fc1t  = ws + 22020096;
  // scan temp buffers reuse xiraw region? NO — xiraw still holds conv input for p1? p1 reads
  // dtb/xib/bcb only; xiraw free after k_convx. Reuse it.
  float* Pb = xiraw;
  float* fb = xiraw + 1048576;
  float* Sb = xiraw + 2097152;
  // classifier buffers reuse xiraw region (free after mamba layers)
  float* c1 = xiraw;
  float* c2 = xiraw + 1048576;
  float* c3 = xiraw + 1572864;
  float* c4 = xiraw + 1835008;
  float* hf = h1;

  k_prep_fc1<<<512, 256, 0, stream>>>(fc1w, fc1t);
  k_front<<<8192, 256, 0, stream>>>(x, dw1, db1, dg1, dbe1, h1);
  k_conv2<<<512, 256, 0, stream>>>(h1, dw2, db2, dg2, dbe2, res);
  for (int il = 0; il < 4; ++il) {
    k_lnproj<<<512, 256, 0, stream>>>(res, lng + il * 64, lnb + il * 64,
                                      inw + il * 16384, xiraw, zb);
    k_convx<<<1024, 256, 0, stream>>>(xiraw, convw + il * 512, convb + il * 128,
                                      xprojw + il * 4608, dtpw + il * 512,
                                      dtpb + il * 128, xib, dtb, bcb);
    k_scan_p1<<<4096, 256, 0, stream>>>(dtb, xib, bcb, alog + il * 2048, Pb, fb);
    k_scan_p2<<<128, 256, 0, stream>>>(Pb, fb, Sb);
    k_scan_p3<<<4096, 256, 0, stream>>>(dtb, xib, bcb, zb, Dp + il * 128,
                                        alog + il * 2048, Sb);
    k_outproj<<<512, 256, 0, stream>>>(dtb, outw + il * 8192, res);
  }
  k_lnfinal<<<8192, 256, 0, stream>>>(res, flng, flnb, hf);
  k_cls<<<256, 256, 0, stream>>>(hf, c1, clsw1, clsb1, clsg1, clsbe1, 2048, 1024, 0);
  k_cls<<<128, 256, 0, stream>>>(c1, c2, clswR + 0 * 20480, clsbR + 0, clsgR + 0,
                                 clsbeR + 0, 1024, 512, 1);
  k_cls<<<64, 256, 0, stream>>>(c2, c3, clswR + 1 * 20480, clsbR + 64, clsgR + 64,
                                clsbeR + 64, 512, 256, 1);
  k_cls<<<32, 256, 0, stream>>>(c3, c4, clswR + 2 * 20480, clsbR + 128, clsgR + 128,
                                clsbeR + 128, 256, 128, 1);
  k_fc<<<16, 256, 0, stream>>>(c4, fc1t, fc1b, fcg, fcbe, fc2w, fc2b, (float*)d_out);
}

// Round 4
// 1180.443 us; speedup vs baseline: 4.5292x; 1.1690x over previous
//
#include <hip/hip_runtime.h>

#define DINL static __device__ __forceinline__

namespace {
constexpr int BN = 16;
constexpr int LQ = 2048;
constexpr int DM = 64;
constexpr int DI = 128;
constexpr float EPS = 1e-5f;
constexpr int NCH = 32;   // scan chunks
constexpr int CT = 64;    // chunk length (NCH*CT == LQ)
}

DINL float sigmoidf_(float x) { return 1.0f / (1.0f + __expf(-x)); }

// ---------------- Stage A: conv1d 1->64 K=3 pad1 + BN + ReLU -> h1 (B,64,L)
__global__ void __launch_bounds__(256) k_front(const float* __restrict__ x,
    const float* __restrict__ w, const float* __restrict__ bb,
    const float* __restrict__ g, const float* __restrict__ be,
    float* __restrict__ h1) {
  int idx = blockIdx.x * 256 + threadIdx.x;   // (b*64+c)*2048 + l
  int l = idx & (LQ - 1);
  int c = (idx >> 11) & 63;
  int b = idx >> 17;
  const float* xr = x + b * LQ;
  float xm = (l > 0) ? xr[l - 1] : 0.0f;
  float x0 = xr[l];
  float xp = (l < LQ - 1) ? xr[l + 1] : 0.0f;
  float acc = w[c * 3 + 0] * xm + w[c * 3 + 1] * x0 + w[c * 3 + 2] * xp + bb[c];
  float v = acc * (g[c] * rsqrtf(1.0f + EPS)) + be[c];
  h1[idx] = fmaxf(v, 0.0f);
}

// ---------------- Stage B: conv1d 64->64 K=3 pad1 + BN + ReLU, write transposed res (B,L,64)
__global__ void __launch_bounds__(256) k_conv2(const float* __restrict__ h1,
    const float* __restrict__ w, const float* __restrict__ bb,
    const float* __restrict__ g, const float* __restrict__ be,
    float* __restrict__ res) {
  __shared__ float xin[64 * 66];   // 64 ci x (64+2)
  __shared__ float wl[32 * 192];   // half the out channels per pass
  __shared__ float os[64 * 65];    // out staging (l, c) padded
  int tid = threadIdx.x;
  int b = blockIdx.x >> 5;
  int t0 = (blockIdx.x & 31) * 64;
  for (int i = tid; i < 64 * 66; i += 256) {
    int ci = i / 66, j = i % 66;
    int l = t0 - 1 + j;
    xin[i] = (l >= 0 && l < LQ) ? h1[(b * 64 + ci) * LQ + l] : 0.0f;
  }
  int wv = tid >> 6, lane = tid & 63;
  float rs = rsqrtf(1.0f + EPS);
  for (int p = 0; p < 2; ++p) {
    __syncthreads();
    for (int i = tid; i < 32 * 192; i += 256) wl[i] = w[p * 32 * 192 + i];
    __syncthreads();
    float acc[8];
#pragma unroll
    for (int i2 = 0; i2 < 8; ++i2) acc[i2] = 0.0f;
    for (int ci = 0; ci < 64; ++ci) {
      float x0 = xin[ci * 66 + lane];
      float x1 = xin[ci * 66 + lane + 1];
      float x2 = xin[ci * 66 + lane + 2];
      const float* wr = &wl[(wv * 8) * 192 + ci * 3];
#pragma unroll
      for (int i2 = 0; i2 < 8; ++i2)
        acc[i2] += wr[i2 * 192 + 0] * x0 + wr[i2 * 192 + 1] * x1 + wr[i2 * 192 + 2] * x2;
    }
#pragma unroll
    for (int i2 = 0; i2 < 8; ++i2) {
      int co = p * 32 + wv * 8 + i2;
      float v = (acc[i2] + bb[co]) * (g[co] * rs) + be[co];
      os[lane * 65 + co] = fmaxf(v, 0.0f);
    }
  }
  __syncthreads();
  for (int i = tid; i < 4096; i += 256) {
    int r = i >> 6, c = i & 63;
    res[(b * LQ + t0 + r) * 64 + c] = os[r * 65 + c];
  }
}

// ---------------- Mamba K1: LayerNorm + in_proj (256x64), split to xi_raw / z
// 64-row tile; thread computes 8 rows x 4 cols; acc[8][4]=32 VGPR; kb unroll 2.
__global__ void __launch_bounds__(256) k_lnproj(const float* __restrict__ res,
    const float* __restrict__ lng, const float* __restrict__ lnb,
    const float* __restrict__ inw, float* __restrict__ xiraw, float* __restrict__ zb) {
  __shared__ float tile[64 * 68];     // row stride 68 (16B aligned); GEMM reads are broadcast
  __shared__ float4 w4[16 * 128];     // [kb][c] for current 128-col half
  __shared__ float gl[64], bl[64];
  int tid = threadIdx.x;
  int b = blockIdx.x >> 5;
  int t0 = (blockIdx.x & 31) * 64;
  const float4* rb0 = (const float4*)(res + (size_t)(b * LQ + t0) * 64);
  for (int i = tid; i < 1024; i += 256) {
    int r = i >> 4, kb = i & 15;
    *(float4*)&tile[r * 68 + kb * 4] = rb0[i];
  }
  if (tid < 64) gl[tid] = lng[tid];
  else if (tid < 128) bl[tid - 64] = lnb[tid - 64];
  __syncthreads();
  // LN: 4 threads per row, stride-4 elements (bank = (tid+4k)%32 -> 2-way, free)
  {
    int row = tid >> 2, part = tid & 3;
    float* tr = &tile[row * 68];
    float s = 0.0f;
#pragma unroll
    for (int k = 0; k < 16; ++k) s += tr[part + 4 * k];
    s += __shfl_xor(s, 1);
    s += __shfl_xor(s, 2);
    float m = s * (1.0f / 64.0f);
    float q = 0.0f;
#pragma unroll
    for (int k = 0; k < 16; ++k) { float dd = tr[part + 4 * k] - m; q += dd * dd; }
    q += __shfl_xor(q, 1);
    q += __shfl_xor(q, 2);
    float iv = rsqrtf(q * (1.0f / 64.0f) + EPS);
#pragma unroll
    for (int k = 0; k < 16; ++k) {
      int c = part + 4 * k;
      tr[c] = (tr[c] - m) * iv * gl[c] + bl[c];
    }
  }
  int ln = tid & 63, wv = tid >> 6;
  int rh = ln >> 5;               // row half within wave
  int c0 = (ln & 31) * 4;         // 4 consecutive cols of the 128-col half
  int r0 = (wv * 2 + rh) * 8;     // 8 rows
  const float4* wsrc = (const float4*)inw;
  for (int p = 0; p < 2; ++p) {
    __syncthreads();
    for (int i = tid; i < 2048; i += 256) {
      int c = i >> 4, kb = i & 15;
      w4[kb * 128 + c] = wsrc[p * 2048 + i];
    }
    __syncthreads();
    float acc[8][4];
#pragma unroll
    for (int rr = 0; rr < 8; ++rr)
#pragma unroll
      for (int cc = 0; cc < 4; ++cc) acc[rr][cc] = 0.0f;
#pragma unroll 2
    for (int kb = 0; kb < 16; ++kb) {
      float4 w0 = w4[kb * 128 + c0 + 0];
      float4 w1 = w4[kb * 128 + c0 + 1];
      float4 w2 = w4[kb * 128 + c0 + 2];
      float4 w3 = w4[kb * 128 + c0 + 3];
#pragma unroll
      for (int rr = 0; rr < 8; ++rr) {
        float4 xv = *(const float4*)&tile[(r0 + rr) * 68 + kb * 4];
        acc[rr][0] += w0.x * xv.x + w0.y * xv.y + w0.z * xv.z + w0.w * xv.w;
        acc[rr][1] += w1.x * xv.x + w1.y * xv.y + w1.z * xv.z + w1.w * xv.w;
        acc[rr][2] += w2.x * xv.x + w2.y * xv.y + w2.z * xv.z + w2.w * xv.w;
        acc[rr][3] += w3.x * xv.x + w3.y * xv.y + w3.z * xv.z + w3.w * xv.w;
      }
    }
    float* outp = (p == 0) ? xiraw : zb;
#pragma unroll
    for (int rr = 0; rr < 8; ++rr) {
      float4 o = make_float4(acc[rr][0], acc[rr][1], acc[rr][2], acc[rr][3]);
      *(float4*)&outp[(size_t)(b * LQ + t0 + r0 + rr) * DI + c0] = o;
    }
  }
}

// ---------------- Mamba K2: causal depthwise conv K=4 + SiLU + x_proj + dt_proj(softplus)
__global__ void __launch_bounds__(256) k_convx(const float* __restrict__ xiraw,
    const float* __restrict__ cw, const float* __restrict__ cb,
    const float* __restrict__ xw, const float* __restrict__ dtw,
    const float* __restrict__ dtbias, float* __restrict__ xib,
    float* __restrict__ dtb, float* __restrict__ bcb) {
  __shared__ float xin[35 * 128];
  __shared__ float xit[32 * 128];
  __shared__ float4 xw4[32 * 37];   // xw4[kb*37 + c] (stride 37: conflict-reduced stage)
  __shared__ float xdbl[32 * 40];
  __shared__ float4 cw4[128];
  __shared__ float cbl[128];
  __shared__ float4 dtw4[128];
  __shared__ float dtbl[128];
  int tid = threadIdx.x;
  int b = blockIdx.x >> 6;
  int t0 = (blockIdx.x & 63) * 32;
  for (int i = tid; i < 1120; i += 256) {     // 35*128/4 float4 loads
    int r = i >> 5, dq = i & 31;
    int l = t0 - 3 + r;
    float4 v = make_float4(0.f, 0.f, 0.f, 0.f);
    if (l >= 0) v = ((const float4*)xiraw)[(size_t)(b * LQ + l) * 32 + dq];
    *(float4*)&xin[r * 128 + dq * 4] = v;
  }
  if (tid < 128) {
    cw4[tid] = ((const float4*)cw)[tid];
    cbl[tid] = cb[tid];
    dtw4[tid] = ((const float4*)dtw)[tid];
    dtbl[tid] = dtbias[tid];
  }
  for (int i = tid; i < 32 * 36; i += 256) {
    xw4[(i & 31) * 37 + (i >> 5)] = ((const float4*)xw)[i];
  }
  __syncthreads();
  for (int i = tid; i < 32 * 128; i += 256) {
    int r = i >> 7, d = i & 127;
    float4 cv = cw4[d];
    float a = cbl[d] + cv.x * xin[r * 128 + d] + cv.y * xin[(r + 1) * 128 + d]
            + cv.z * xin[(r + 2) * 128 + d] + cv.w * xin[(r + 3) * 128 + d];
    float v = a * sigmoidf_(a);
    xit[i] = v;
    xib[(size_t)(b * LQ + t0 + r) * DI + d] = v;
  }
  __syncthreads();
  int wv = tid >> 6, lane = tid & 63;
  if (lane < 36) {
    int r0 = wv * 8;
    float acc[8];
#pragma unroll
    for (int rr = 0; rr < 8; ++rr) acc[rr] = 0.0f;
#pragma unroll 4
    for (int kb = 0; kb < 32; ++kb) {
      float4 wvv = xw4[kb * 37 + lane];
#pragma unroll
      for (int rr = 0; rr < 8; ++rr) {
        float4 xv = *(const float4*)&xit[(r0 + rr) * 128 + kb * 4];
        acc[rr] += wvv.x * xv.x + wvv.y * xv.y + wvv.z * xv.z + wvv.w * xv.w;
      }
    }
#pragma unroll
    for (int rr = 0; rr < 8; ++rr) xdbl[(r0 + rr) * 40 + lane] = acc[rr];
  }
  __syncthreads();
  for (int i = tid; i < 32 * 128; i += 256) {
    int r = i >> 7, d = i & 127;
    float4 wvv = dtw4[d];
    float4 xd = *(const float4*)&xdbl[r * 40];
    float sv = dtbl[d] + wvv.x * xd.x + wvv.y * xd.y + wvv.z * xd.z + wvv.w * xd.w;
    dtb[(size_t)(b * LQ + t0 + r) * DI + d] = (sv > 20.0f) ? sv : log1pf(__expf(sv));
  }
  for (int i = tid; i < 32 * 32; i += 256) {
    int r = i >> 5, j = i & 31;
    bcb[(size_t)(b * LQ + t0 + r) * 32 + j] = xdbl[r * 40 + 4 + j];
  }
}

// ---------------- Mamba K3a: chunked scan phase 1 — per-chunk (P = prod a, f = local state)
__global__ void __launch_bounds__(256) k_scan_p1(const float* __restrict__ dtb,
    const float* __restrict__ xib, const float* __restrict__ bcb,
    const float* __restrict__ alog, float* __restrict__ Pb, float* __restrict__ fb) {
  __shared__ float sdt[CT * 16], sx[CT * 16], sbc[CT * 32];
  int blk = blockIdx.x;
  int c = blk & 31, dg = (blk >> 5) & 7, b = blk >> 8;
  int tid = threadIdx.x;
  int ln = tid & 63;
  int dl = (tid >> 6) * 4 + (ln >> 4);
  int j = ln & 15;
  int t0 = c * CT;
  size_t rowb = (size_t)(b * LQ + t0);
  for (int i = tid; i < CT * 4; i += 256) {
    int r = i >> 2, q = i & 3;
    ((float4*)sdt)[i] = *(const float4*)&dtb[(rowb + r) * DI + dg * 16 + q * 4];
    ((float4*)sx)[i]  = *(const float4*)&xib[(rowb + r) * DI + dg * 16 + q * 4];
  }
  for (int i = tid; i < CT * 8; i += 256) {
    int r = i >> 3, q = i & 7;
    ((float4*)sbc)[i] = *(const float4*)&bcb[(rowb + r) * 32 + q * 4];
  }
  float A2 = -__expf(alog[(dg * 16 + dl) * 16 + j]) * 1.4426950408889634f;
  __syncthreads();
  float P = 1.0f, s = 0.0f;
#pragma unroll 4
  for (int tt = 0; tt < CT; ++tt) {
    float dtv = sdt[tt * 16 + dl];
    float xv  = sx[tt * 16 + dl];
    float Bv  = sbc[tt * 32 + j];
    float a = exp2f(dtv * A2);
    P *= a;
    s = a * s + (dtv * xv) * Bv;
  }
  Pb[(size_t)blk * 256 + tid] = P;
  fb[(size_t)blk * 256 + tid] = s;
}

// ---------------- Mamba K3b: sequential combine over chunks -> chunk-start states
__global__ void __launch_bounds__(256) k_scan_p2(const float* __restrict__ Pb,
    const float* __restrict__ fb, float* __restrict__ Sb) {
  int idx = blockIdx.x * 256 + threadIdx.x;   // (b*8+dg)*256 + r
  int grp = idx >> 8, r = idx & 255;
  float s = 0.0f;
  for (int c = 0; c < NCH; ++c) {
    size_t a = ((size_t)grp * NCH + c) * 256 + r;
    Sb[a] = s;
    s = Pb[a] * s + fb[a];
  }
}

// ---------------- Mamba K3c: re-run recurrence from Sstart; emit GATED y in-place into dtb:
// y = (scan_out + xi*Dp) * silu(z)
__global__ void __launch_bounds__(256) k_scan_p3(float* __restrict__ dtb,
    const float* __restrict__ xib, const float* __restrict__ bcb,
    const float* __restrict__ zb, const float* __restrict__ Dpl,
    const float* __restrict__ alog, const float* __restrict__ Sb) {
  __shared__ float sdt[CT * 16], sx[CT * 16], sbc[CT * 32], sz[CT * 16];
  __shared__ float yt[CT * 16];
  int blk = blockIdx.x;
  int c = blk & 31, dg = (blk >> 5) & 7, b = blk >> 8;
  int tid = threadIdx.x;
  int ln = tid & 63;
  int dl = (tid >> 6) * 4 + (ln >> 4);
  int j = ln & 15;
  int t0 = c * CT;
  size_t rowb = (size_t)(b * LQ + t0);
  for (int i = tid; i < CT * 4; i += 256) {
    int r = i >> 2, q = i & 3;
    ((float4*)sdt)[i] = *(const float4*)&dtb[(rowb + r) * DI + dg * 16 + q * 4];
    ((float4*)sx)[i]  = *(const float4*)&xib[(rowb + r) * DI + dg * 16 + q * 4];
    ((float4*)sz)[i]  = *(const float4*)&zb[(rowb + r) * DI + dg * 16 + q * 4];
  }
  for (int i = tid; i < CT * 8; i += 256) {
    int r = i >> 3, q = i & 7;
    ((float4*)sbc)[i] = *(const float4*)&bcb[(rowb + r) * 32 + q * 4];
  }
  float A2 = -__expf(alog[(dg * 16 + dl) * 16 + j]) * 1.4426950408889634f;
  float Dv = Dpl[dg * 16 + dl];
  float s = Sb[(size_t)blk * 256 + tid];
  __syncthreads();
#pragma unroll 4
  for (int tt = 0; tt < CT; ++tt) {
    float dtv = sdt[tt * 16 + dl];
    float xv  = sx[tt * 16 + dl];
    float Bv  = sbc[tt * 32 + j];
    float Cv  = sbc[tt * 32 + 16 + j];
    float a = exp2f(dtv * A2);
    s = a * s + (dtv * xv) * Bv;
    float p = s * Cv;
    p += __shfl_xor(p, 1);
    p += __shfl_xor(p, 2);
    p += __shfl_xor(p, 4);
    p += __shfl_xor(p, 8);
    if (j == 0) {
      float zv = sz[tt * 16 + dl];
      yt[tt * 16 + dl] = (p + xv * Dv) * zv * sigmoidf_(zv);
    }
  }
  __syncthreads();
  for (int i = tid; i < CT * 4; i += 256) {
    int r = i >> 2, q = i & 3;
    *(float4*)&dtb[(rowb + r) * DI + dg * 16 + q * 4] = ((float4*)yt)[i];
  }
}

// ---------------- Mamba K4: out_proj (64 out x 128 k) on gated activations; res +=
__global__ void __launch_bounds__(256, 2) k_outproj(const float* __restrict__ gt_g,
    const float* __restrict__ outw, float* __restrict__ res) {
  __shared__ float gt[64 * 128];
  __shared__ float4 w4s[32 * 64];   // w4s[kb*64 + (c+kb)&63] (swizzled stage)
  int tid = threadIdx.x;
  int b = blockIdx.x >> 5;
  int t0 = (blockIdx.x & 31) * 64;
  size_t base = (size_t)(b * LQ + t0) * DI;
  const float4* src4 = (const float4*)(gt_g + base);
  for (int i = tid; i < 2048; i += 256)
    ((float4*)gt)[i] = src4[i];
  for (int i = tid; i < 2048; i += 256) {
    int c = i >> 5, kb = i & 31;
    w4s[kb * 64 + ((c + kb) & 63)] = ((const float4*)outw)[i];
  }
  __syncthreads();
  int wv = tid >> 6, lane = tid & 63;
  int r0 = wv * 16;
  float acc[16];
#pragma unroll
  for (int rr = 0; rr < 16; ++rr) acc[rr] = 0.0f;
#pragma unroll 2
  for (int kb = 0; kb < 32; ++kb) {
    float4 wvv = w4s[kb * 64 + ((lane + kb) & 63)];
#pragma unroll
    for (int rr = 0; rr < 16; ++rr) {
      float4 xv = *(const float4*)&gt[(r0 + rr) * 128 + kb * 4];
      acc[rr] += wvv.x * xv.x + wvv.y * xv.y + wvv.z * xv.z + wvv.w * xv.w;
    }
  }
#pragma unroll
  for (int rr = 0; rr < 16; ++rr)
    res[(size_t)(b * LQ + t0 + r0 + rr) * 64 + lane] += acc[rr];
}

// ---------------- Final LayerNorm: res -> hf, one wave per row
__global__ void __launch_bounds__(256) k_lnfinal(const float* __restrict__ res,
    const float* __restrict__ g, const float* __restrict__ bb, float* __restrict__ hf) {
  int row = blockIdx.x * 4 + (threadIdx.x >> 6);
  int lane = threadIdx.x & 63;
  float v = res[row * 64 + lane];
  float s = v;
#pragma unroll
  for (int m = 32; m >= 1; m >>= 1) s += __shfl_xor(s, m);
  float mean = s * (1.0f / 64.0f);
  float dd = v - mean;
  float q = dd * dd;
#pragma unroll
  for (int m = 32; m >= 1; m >>= 1) q += __shfl_xor(q, m);
  float iv = rsqrtf(q * (1.0f / 64.0f) + EPS);
  hf[row * 64 + lane] = dd * iv * g[lane] + bb[lane];
}

// ---------------- Classifier conv: 64->64 K=5 stride2 pad2 + BN + ReLU
__global__ void __launch_bounds__(256) k_cls(const float* __restrict__ in,
    float* __restrict__ out, const float* __restrict__ w,
    const float* __restrict__ bb, const float* __restrict__ g,
    const float* __restrict__ be, int Lin, int Lout, int layout) {
  __shared__ float xin[64 * 136];   // 64 ci x 131 (span), padded
  __shared__ float wl[16 * 320];    // 16 out-ch per pass
  int tid = threadIdx.x;
  int tilesPerB = Lout >> 6;
  int b = blockIdx.x / tilesPerB;
  int t0 = (blockIdx.x % tilesPerB) * 64;
  int lbase = 2 * t0 - 2;
  if (layout == 0) {
    for (int i = tid; i < 64 * 131; i += 256) {
      int lr = i >> 6, ci = i & 63;
      int l = lbase + lr;
      xin[ci * 136 + lr] = (l >= 0 && l < Lin) ? in[(b * Lin + l) * 64 + ci] : 0.0f;
    }
  } else {
    for (int i = tid; i < 64 * 132; i += 256) {
      int ci = i / 132, lr = i % 132;
      if (lr < 131) {
        int l = lbase + lr;
        xin[ci * 136 + lr] = (l >= 0 && l < Lin) ? in[(b * 64 + ci) * Lin + l] : 0.0f;
      }
    }
  }
  int wv = tid >> 6, lane = tid & 63;
  float rs = rsqrtf(1.0f + EPS);
  for (int p = 0; p < 4; ++p) {
    __syncthreads();
    for (int i = tid; i < 16 * 320; i += 256) wl[i] = w[p * 16 * 320 + i];
    __syncthreads();
    float acc[4] = {0.0f, 0.0f, 0.0f, 0.0f};
    for (int ci = 0; ci < 64; ++ci) {
      const float* xr = &xin[ci * 136 + 2 * lane];
      float v0 = xr[0], v1 = xr[1], v2 = xr[2], v3 = xr[3], v4 = xr[4];
      const float* wr = &wl[(wv * 4) * 320 + ci * 5];
#pragma unroll
      for (int i2 = 0; i2 < 4; ++i2) {
        acc[i2] += wr[i2 * 320 + 0] * v0 + wr[i2 * 320 + 1] * v1 + wr[i2 * 320 + 2] * v2
                 + wr[i2 * 320 + 3] * v3 + wr[i2 * 320 + 4] * v4;
      }
    }
#pragma unroll
    for (int i2 = 0; i2 < 4; ++i2) {
      int co = p * 16 + wv * 4 + i2;
      float v = (acc[i2] + bb[co]) * (g[co] * rs) + be[co];
      out[(b * 64 + co) * Lout + t0 + lane] = fmaxf(v, 0.0f);
    }
  }
}

// ---------------- fc1 weight transpose prep
__global__ void __launch_bounds__(256) k_prep_fc1(const float* __restrict__ w,
                                                  float* __restrict__ wt) {
  int i = blockIdx.x * 256 + threadIdx.x;   // i < 131072
  int kb = i >> 8, f = i & 255;
  ((float4*)wt)[i] = ((const float4*)w)[f * 512 + kb];
}

// ---------------- Pool + FC1 + BN + ReLU + FC2
__global__ void __launch_bounds__(256) k_fc(const float* __restrict__ cin,
    const float* __restrict__ w1t, const float* __restrict__ b1,
    const float* __restrict__ g, const float* __restrict__ be,
    const float* __restrict__ w2, const float* __restrict__ b2,
    float* __restrict__ dout) {
  __shared__ float pooled[2048];
  __shared__ float feat[256];
  int tid = threadIdx.x;
  int b = blockIdx.x;
  for (int i = tid; i < 2048; i += 256) {
    float4 v = ((const float4*)cin)[b * 2048 + i];
    pooled[i] = (v.x + v.y + v.z + v.w) * 0.25f;
  }
  __syncthreads();
  float acc = b1[tid];
  const float4* wt4 = (const float4*)w1t;
  for (int kb = 0; kb < 512; ++kb) {
    float4 wv = wt4[kb * 256 + tid];
    float4 pv = *(const float4*)&pooled[kb * 4];
    acc += wv.x * pv.x + wv.y * pv.y + wv.z * pv.z + wv.w * pv.w;
  }
  float v = acc * (g[tid] * rsqrtf(1.0f + EPS)) + be[tid];
  feat[tid] = fmaxf(v, 0.0f);
  __syncthreads();
  if (tid < 5) {
    float a2 = b2[tid];
    for (int k = 0; k < 256; ++k) a2 += w2[tid * 256 + k] * feat[k];
    dout[b * 5 + tid] = a2;
  }
}

extern "C" void kernel_launch(void* const* d_in, const int* in_sizes, int n_in,
                              void* d_out, int out_size, void* d_ws, size_t ws_size,
                              hipStream_t stream) {
  (void)in_sizes; (void)n_in; (void)out_size; (void)ws_size;
  const float* x      = (const float*)d_in[0];
  const float* dw1    = (const float*)d_in[1];
  const float* db1    = (const float*)d_in[2];
  const float* dg1    = (const float*)d_in[3];
  const float* dbe1   = (const float*)d_in[4];
  const float* dw2    = (const float*)d_in[5];
  const float* db2    = (const float*)d_in[6];
  const float* dg2    = (const float*)d_in[7];
  const float* dbe2   = (const float*)d_in[8];
  const float* lng    = (const float*)d_in[9];
  const float* lnb    = (const float*)d_in[10];
  const float* inw    = (const float*)d_in[11];
  const float* convw  = (const float*)d_in[12];
  const float* convb  = (const float*)d_in[13];
  const float* xprojw = (const float*)d_in[14];
  const float* dtpw   = (const float*)d_in[15];
  const float* dtpb   = (const float*)d_in[16];
  const float* alog   = (const float*)d_in[17];
  const float* Dp     = (const float*)d_in[18];
  const float* outw   = (const float*)d_in[19];
  const float* flng   = (const float*)d_in[20];
  const float* flnb   = (const float*)d_in[21];
  const float* clsw1  = (const float*)d_in[22];
  const float* clsb1  = (const float*)d_in[23];
  const float* clsg1  = (const float*)d_in[24];
  const float* clsbe1 = (const float*)d_in[25];
  const float* clswR  = (const float*)d_in[26];
  const float* clsbR  = (const float*)d_in[27];
  const float* clsgR  = (const float*)d_in[28];
  const float* clsbeR = (const float*)d_in[29];
  const float* fc1w   = (const float*)d_in[30];
  const float* fc1b   = (const float*)d_in[31];
  const float* fcg    = (const float*)d_in[32];
  const float* fcbe   = (const float*)d_in[33];
  const float* fc2w   = (const float*)d_in[34];
  const float* fc2b   = (const float*)d_in[35];

  float* ws = (float*)d_ws;
  float* h1    = ws;                    // (B,64,L); reused as hf later
  float* res   = ws + 2097152;          // (B,L,64)
  float* xiraw = ws + 4194304;          // (B,L,128)
  float* zb    = ws + 8388608;
  float* xib   = ws + 12582912;
  float* dtb   = ws + 16777216;         // dt -> gated y (in-place through scan)
  float* bcb   = ws + 20971520;         // (B,L,32)
  float* fc1t  = ws + 22020096;
  float* Pb = xiraw;                    // scan temps reuse xiraw (free after k_convx)
  float* fb = xiraw + 1048576;
  float* Sb = xiraw + 2097152;
  float* c1 = xiraw;                    // classifier bufs reuse xiraw
  float* c2 = xiraw + 1048576;
  float* c3 = xiraw + 1572864;
  float* c4 = xiraw + 1835008;
  float* hf = h1;

  k_prep_fc1<<<512, 256, 0, stream>>>(fc1w, fc1t);
  k_front<<<8192, 256, 0, stream>>>(x, dw1, db1, dg1, dbe1, h1);
  k_conv2<<<512, 256, 0, stream>>>(h1, dw2, db2, dg2, dbe2, res);
  for (int il = 0; il < 4; ++il) {
    k_lnproj<<<512, 256, 0, stream>>>(res, lng + il * 64, lnb + il * 64,
                                      inw + il * 16384, xiraw, zb);
    k_convx<<<1024, 256, 0, stream>>>(xiraw, convw + il * 512, convb + il * 128,
                                      xprojw + il * 4608, dtpw + il * 512,
                                      dtpb + il * 128, xib, dtb, bcb);
    k_scan_p1<<<4096, 256, 0, stream>>>(dtb, xib, bcb, alog + il * 2048, Pb, fb);
    k_scan_p2<<<128, 256, 0, stream>>>(Pb, fb, Sb);
    k_scan_p3<<<4096, 256, 0, stream>>>(dtb, xib, bcb, zb, Dp + il * 128,
                                        alog + il * 2048, Sb);
    k_outproj<<<512, 256, 0, stream>>>(dtb, outw + il * 8192, res);
  }
  k_lnfinal<<<8192, 256, 0, stream>>>(res, flng, flnb, hf);
  k_cls<<<256, 256, 0, stream>>>(hf, c1, clsw1, clsb1, clsg1, clsbe1, 2048, 1024, 0);
  k_cls<<<128, 256, 0, stream>>>(c1, c2, clswR + 0 * 20480, clsbR + 0, clsgR + 0,
                                 clsbeR + 0, 1024, 512, 1);
  k_cls<<<64, 256, 0, stream>>>(c2, c3, clswR + 1 * 20480, clsbR + 64, clsgR + 64,
                                clsbeR + 64, 512, 256, 1);
  k_cls<<<32, 256, 0, stream>>>(c3, c4, clswR + 2 * 20480, clsbR + 128, clsgR + 128,
                                clsbeR + 128, 256, 128, 1);
  k_fc<<<16, 256, 0, stream>>>(c4, fc1t, fc1b, fcg, fcbe, fc2w, fc2b, (float*)d_out);
}

// Round 5
// 1069.899 us; speedup vs baseline: 4.9971x; 1.1033x over previous
//
#include <hip/hip_runtime.h>

#define DINL static __device__ __forceinline__

namespace {
constexpr int BN = 16;
constexpr int LQ = 2048;
constexpr int DM = 64;
constexpr int DI = 128;
constexpr float EPS = 1e-5f;
constexpr int NCH = 64;   // scan chunks
constexpr int CT = 32;    // chunk length (NCH*CT == LQ)
constexpr float LOG2E = 1.4426950408889634f;
}

DINL float sigmoidf_(float x) { return 1.0f / (1.0f + __expf(-x)); }

// ---------------- Stage A: conv1d 1->64 K=3 pad1 + BN + ReLU -> h1 (B,64,L)
__global__ void __launch_bounds__(256) k_front(const float* __restrict__ x,
    const float* __restrict__ w, const float* __restrict__ bb,
    const float* __restrict__ g, const float* __restrict__ be,
    float* __restrict__ h1) {
  int idx = blockIdx.x * 256 + threadIdx.x;   // (b*64+c)*2048 + l
  int l = idx & (LQ - 1);
  int c = (idx >> 11) & 63;
  int b = idx >> 17;
  const float* xr = x + b * LQ;
  float xm = (l > 0) ? xr[l - 1] : 0.0f;
  float x0 = xr[l];
  float xp = (l < LQ - 1) ? xr[l + 1] : 0.0f;
  float acc = w[c * 3 + 0] * xm + w[c * 3 + 1] * x0 + w[c * 3 + 2] * xp + bb[c];
  float v = acc * (g[c] * rsqrtf(1.0f + EPS)) + be[c];
  h1[idx] = fmaxf(v, 0.0f);
}

// ---------------- Stage B: conv1d 64->64 K=3 pad1 + BN + ReLU, write transposed res (B,L,64)
__global__ void __launch_bounds__(256) k_conv2(const float* __restrict__ h1,
    const float* __restrict__ w, const float* __restrict__ bb,
    const float* __restrict__ g, const float* __restrict__ be,
    float* __restrict__ res) {
  __shared__ float xin[64 * 66];   // 64 ci x (64+2)
  __shared__ float wl[32 * 192];   // half the out channels per pass
  __shared__ float os[64 * 65];    // out staging (l, c) padded
  int tid = threadIdx.x;
  int b = blockIdx.x >> 5;
  int t0 = (blockIdx.x & 31) * 64;
  for (int i = tid; i < 64 * 66; i += 256) {
    int ci = i / 66, j = i % 66;
    int l = t0 - 1 + j;
    xin[i] = (l >= 0 && l < LQ) ? h1[(b * 64 + ci) * LQ + l] : 0.0f;
  }
  int wv = tid >> 6, lane = tid & 63;
  float rs = rsqrtf(1.0f + EPS);
  for (int p = 0; p < 2; ++p) {
    __syncthreads();
    for (int i = tid; i < 32 * 192; i += 256) wl[i] = w[p * 32 * 192 + i];
    __syncthreads();
    float acc[8];
#pragma unroll
    for (int i2 = 0; i2 < 8; ++i2) acc[i2] = 0.0f;
    for (int ci = 0; ci < 64; ++ci) {
      float x0 = xin[ci * 66 + lane];
      float x1 = xin[ci * 66 + lane + 1];
      float x2 = xin[ci * 66 + lane + 2];
      const float* wr = &wl[(wv * 8) * 192 + ci * 3];
#pragma unroll
      for (int i2 = 0; i2 < 8; ++i2)
        acc[i2] += wr[i2 * 192 + 0] * x0 + wr[i2 * 192 + 1] * x1 + wr[i2 * 192 + 2] * x2;
    }
#pragma unroll
    for (int i2 = 0; i2 < 8; ++i2) {
      int co = p * 32 + wv * 8 + i2;
      float v = (acc[i2] + bb[co]) * (g[co] * rs) + be[co];
      os[lane * 65 + co] = fmaxf(v, 0.0f);
    }
  }
  __syncthreads();
  for (int i = tid; i < 4096; i += 256) {
    int r = i >> 6, c = i & 63;
    res[(b * LQ + t0 + r) * 64 + c] = os[r * 65 + c];
  }
}

// ---------------- Mamba K1: LayerNorm + in_proj (256x64), split to xi_raw / z
__global__ void __launch_bounds__(256) k_lnproj(const float* __restrict__ res,
    const float* __restrict__ lng, const float* __restrict__ lnb,
    const float* __restrict__ inw, float* __restrict__ xiraw, float* __restrict__ zb) {
  __shared__ float tile[64 * 68];
  __shared__ float4 w4[16 * 128];
  __shared__ float gl[64], bl[64];
  int tid = threadIdx.x;
  int b = blockIdx.x >> 5;
  int t0 = (blockIdx.x & 31) * 64;
  const float4* rb0 = (const float4*)(res + (size_t)(b * LQ + t0) * 64);
  for (int i = tid; i < 1024; i += 256) {
    int r = i >> 4, kb = i & 15;
    *(float4*)&tile[r * 68 + kb * 4] = rb0[i];
  }
  if (tid < 64) gl[tid] = lng[tid];
  else if (tid < 128) bl[tid - 64] = lnb[tid - 64];
  __syncthreads();
  {
    int row = tid >> 2, part = tid & 3;
    float* tr = &tile[row * 68];
    float s = 0.0f;
#pragma unroll
    for (int k = 0; k < 16; ++k) s += tr[part + 4 * k];
    s += __shfl_xor(s, 1);
    s += __shfl_xor(s, 2);
    float m = s * (1.0f / 64.0f);
    float q = 0.0f;
#pragma unroll
    for (int k = 0; k < 16; ++k) { float dd = tr[part + 4 * k] - m; q += dd * dd; }
    q += __shfl_xor(q, 1);
    q += __shfl_xor(q, 2);
    float iv = rsqrtf(q * (1.0f / 64.0f) + EPS);
#pragma unroll
    for (int k = 0; k < 16; ++k) {
      int c = part + 4 * k;
      tr[c] = (tr[c] - m) * iv * gl[c] + bl[c];
    }
  }
  int ln = tid & 63, wv = tid >> 6;
  int rh = ln >> 5;
  int c0 = (ln & 31) * 4;
  int r0 = (wv * 2 + rh) * 8;
  const float4* wsrc = (const float4*)inw;
  for (int p = 0; p < 2; ++p) {
    __syncthreads();
    for (int i = tid; i < 2048; i += 256) {
      int c = i >> 4, kb = i & 15;
      w4[kb * 128 + c] = wsrc[p * 2048 + i];
    }
    __syncthreads();
    float acc[8][4];
#pragma unroll
    for (int rr = 0; rr < 8; ++rr)
#pragma unroll
      for (int cc = 0; cc < 4; ++cc) acc[rr][cc] = 0.0f;
#pragma unroll 2
    for (int kb = 0; kb < 16; ++kb) {
      float4 w0 = w4[kb * 128 + c0 + 0];
      float4 w1 = w4[kb * 128 + c0 + 1];
      float4 w2 = w4[kb * 128 + c0 + 2];
      float4 w3 = w4[kb * 128 + c0 + 3];
#pragma unroll
      for (int rr = 0; rr < 8; ++rr) {
        float4 xv = *(const float4*)&tile[(r0 + rr) * 68 + kb * 4];
        acc[rr][0] += w0.x * xv.x + w0.y * xv.y + w0.z * xv.z + w0.w * xv.w;
        acc[rr][1] += w1.x * xv.x + w1.y * xv.y + w1.z * xv.z + w1.w * xv.w;
        acc[rr][2] += w2.x * xv.x + w2.y * xv.y + w2.z * xv.z + w2.w * xv.w;
        acc[rr][3] += w3.x * xv.x + w3.y * xv.y + w3.z * xv.z + w3.w * xv.w;
      }
    }
    float* outp = (p == 0) ? xiraw : zb;
#pragma unroll
    for (int rr = 0; rr < 8; ++rr) {
      float4 o = make_float4(acc[rr][0], acc[rr][1], acc[rr][2], acc[rr][3]);
      *(float4*)&outp[(size_t)(b * LQ + t0 + r0 + rr) * DI + c0] = o;
    }
  }
}

// ---------------- Mamba K2: causal depthwise conv K=4 + SiLU + x_proj + dt_proj(softplus)
__global__ void __launch_bounds__(256) k_convx(const float* __restrict__ xiraw,
    const float* __restrict__ cw, const float* __restrict__ cb,
    const float* __restrict__ xw, const float* __restrict__ dtw,
    const float* __restrict__ dtbias, float* __restrict__ xib,
    float* __restrict__ dtb, float* __restrict__ bcb) {
  __shared__ float xin[35 * 128];
  __shared__ float xit[32 * 128];
  __shared__ float4 xw4[32 * 37];
  __shared__ float xdbl[32 * 40];
  __shared__ float4 cw4[128];
  __shared__ float cbl[128];
  __shared__ float4 dtw4[128];
  __shared__ float dtbl[128];
  int tid = threadIdx.x;
  int b = blockIdx.x >> 6;
  int t0 = (blockIdx.x & 63) * 32;
  for (int i = tid; i < 1120; i += 256) {
    int r = i >> 5, dq = i & 31;
    int l = t0 - 3 + r;
    float4 v = make_float4(0.f, 0.f, 0.f, 0.f);
    if (l >= 0) v = ((const float4*)xiraw)[(size_t)(b * LQ + l) * 32 + dq];
    *(float4*)&xin[r * 128 + dq * 4] = v;
  }
  if (tid < 128) {
    cw4[tid] = ((const float4*)cw)[tid];
    cbl[tid] = cb[tid];
    dtw4[tid] = ((const float4*)dtw)[tid];
    dtbl[tid] = dtbias[tid];
  }
  for (int i = tid; i < 32 * 36; i += 256) {
    xw4[(i & 31) * 37 + (i >> 5)] = ((const float4*)xw)[i];
  }
  __syncthreads();
  for (int i = tid; i < 32 * 128; i += 256) {
    int r = i >> 7, d = i & 127;
    float4 cv = cw4[d];
    float a = cbl[d] + cv.x * xin[r * 128 + d] + cv.y * xin[(r + 1) * 128 + d]
            + cv.z * xin[(r + 2) * 128 + d] + cv.w * xin[(r + 3) * 128 + d];
    float v = a * sigmoidf_(a);
    xit[i] = v;
    xib[(size_t)(b * LQ + t0 + r) * DI + d] = v;
  }
  __syncthreads();
  int wv = tid >> 6, lane = tid & 63;
  if (lane < 36) {
    int r0 = wv * 8;
    float acc[8];
#pragma unroll
    for (int rr = 0; rr < 8; ++rr) acc[rr] = 0.0f;
#pragma unroll 4
    for (int kb = 0; kb < 32; ++kb) {
      float4 wvv = xw4[kb * 37 + lane];
#pragma unroll
      for (int rr = 0; rr < 8; ++rr) {
        float4 xv = *(const float4*)&xit[(r0 + rr) * 128 + kb * 4];
        acc[rr] += wvv.x * xv.x + wvv.y * xv.y + wvv.z * xv.z + wvv.w * xv.w;
      }
    }
#pragma unroll
    for (int rr = 0; rr < 8; ++rr) xdbl[(r0 + rr) * 40 + lane] = acc[rr];
  }
  __syncthreads();
  for (int i = tid; i < 32 * 128; i += 256) {
    int r = i >> 7, d = i & 127;
    float4 wvv = dtw4[d];
    float4 xd = *(const float4*)&xdbl[r * 40];
    float sv = dtbl[d] + wvv.x * xd.x + wvv.y * xd.y + wvv.z * xd.z + wvv.w * xd.w;
    dtb[(size_t)(b * LQ + t0 + r) * DI + d] = (sv > 20.0f) ? sv : log1pf(__expf(sv));
  }
  for (int i = tid; i < 32 * 32; i += 256) {
    int r = i >> 5, j = i & 31;
    bcb[(size_t)(b * LQ + t0 + r) * 32 + j] = xdbl[r * 40 + 4 + j];
  }
}

// ---------------- Mamba K3a: chunk-local scan; states in registers, 1 thread per (b,d,chunk)
// Stores f[16] (local end state) and sumdt (decay via exp2(A*sum_dt)).
__global__ void __launch_bounds__(128) k_scan_p1(const float* __restrict__ dtb,
    const float* __restrict__ xib, const float* __restrict__ bcb,
    const float* __restrict__ alog, float* __restrict__ sumdt, float* __restrict__ fb) {
  __shared__ float sB[CT * 16];
  int blk = blockIdx.x;
  int c = blk & (NCH - 1), b = blk >> 6;
  int d = threadIdx.x;
  size_t rowb = (size_t)(b * LQ + c * CT);
  for (int i = d; i < CT * 4; i += 128) {
    int r = i >> 2, q = i & 3;
    ((float4*)sB)[i] = ((const float4*)bcb)[(rowb + r) * 8 + q];
  }
  float A2[16];
  const float4* al4 = (const float4*)alog;
#pragma unroll
  for (int q = 0; q < 4; ++q) {
    float4 a = al4[d * 4 + q];
    A2[q * 4 + 0] = -__expf(a.x) * LOG2E;
    A2[q * 4 + 1] = -__expf(a.y) * LOG2E;
    A2[q * 4 + 2] = -__expf(a.z) * LOG2E;
    A2[q * 4 + 3] = -__expf(a.w) * LOG2E;
  }
  float s[16];
#pragma unroll
  for (int j = 0; j < 16; ++j) s[j] = 0.0f;
  float sdt = 0.0f;
  __syncthreads();
#pragma unroll 2
  for (int t = 0; t < CT; ++t) {
    float dtv = dtb[(rowb + t) * DI + d];
    float xv  = xib[(rowb + t) * DI + d];
    sdt += dtv;
    float u = dtv * xv;
#pragma unroll
    for (int q = 0; q < 4; ++q) {
      float4 Bq = *(const float4*)&sB[t * 16 + q * 4];
      s[q * 4 + 0] = exp2f(dtv * A2[q * 4 + 0]) * s[q * 4 + 0] + u * Bq.x;
      s[q * 4 + 1] = exp2f(dtv * A2[q * 4 + 1]) * s[q * 4 + 1] + u * Bq.y;
      s[q * 4 + 2] = exp2f(dtv * A2[q * 4 + 2]) * s[q * 4 + 2] + u * Bq.z;
      s[q * 4 + 3] = exp2f(dtv * A2[q * 4 + 3]) * s[q * 4 + 3] + u * Bq.w;
    }
  }
  size_t ob = (size_t)(b * NCH + c) * DI + d;
  sumdt[ob] = sdt;
#pragma unroll
  for (int q = 0; q < 4; ++q) {
    float4 o = make_float4(s[q * 4 + 0], s[q * 4 + 1], s[q * 4 + 2], s[q * 4 + 3]);
    *(float4*)&fb[ob * 16 + q * 4] = o;
  }
}

// ---------------- Mamba K3b: sequential combine over chunks -> chunk-start states
__global__ void __launch_bounds__(256) k_scan_p2(const float* __restrict__ sumdt,
    const float* __restrict__ fb, const float* __restrict__ alog,
    float* __restrict__ Sb) {
  int idx = blockIdx.x * 256 + threadIdx.x;   // < 16*128*16
  int j = idx & 15, d = (idx >> 4) & 127, b = idx >> 11;
  float A2 = -__expf(alog[d * 16 + j]) * LOG2E;
  float s = 0.0f;
  for (int c = 0; c < NCH; ++c) {
    size_t base = (size_t)(b * NCH + c) * DI + d;
    Sb[base * 16 + j] = s;
    s = exp2f(A2 * sumdt[base]) * s + fb[base * 16 + j];
  }
}

// ---------------- Mamba K3c: re-run recurrence from Sstart (registers); emit GATED y
// in-place into dtb: y = (scan_out + xi*Dp) * silu(z)
__global__ void __launch_bounds__(128) k_scan_p3(float* __restrict__ dtb,
    const float* __restrict__ xib, const float* __restrict__ bcb,
    const float* __restrict__ zb, const float* __restrict__ Dpl,
    const float* __restrict__ alog, const float* __restrict__ Sb) {
  __shared__ float sbc[CT * 32];
  int blk = blockIdx.x;
  int c = blk & (NCH - 1), b = blk >> 6;
  int d = threadIdx.x;
  size_t rowb = (size_t)(b * LQ + c * CT);
  for (int i = d; i < CT * 8; i += 128)
    ((float4*)sbc)[i] = ((const float4*)bcb)[rowb * 8 + i];   // rows contiguous
  float A2[16];
  const float4* al4 = (const float4*)alog;
#pragma unroll
  for (int q = 0; q < 4; ++q) {
    float4 a = al4[d * 4 + q];
    A2[q * 4 + 0] = -__expf(a.x) * LOG2E;
    A2[q * 4 + 1] = -__expf(a.y) * LOG2E;
    A2[q * 4 + 2] = -__expf(a.z) * LOG2E;
    A2[q * 4 + 3] = -__expf(a.w) * LOG2E;
  }
  float Dv = Dpl[d];
  float s[16];
  size_t ob = ((size_t)(b * NCH + c) * DI + d) * 16;
#pragma unroll
  for (int q = 0; q < 4; ++q) {
    float4 v = *(const float4*)&Sb[ob + q * 4];
    s[q * 4 + 0] = v.x; s[q * 4 + 1] = v.y; s[q * 4 + 2] = v.z; s[q * 4 + 3] = v.w;
  }
  __syncthreads();
#pragma unroll 2
  for (int t = 0; t < CT; ++t) {
    float dtv = dtb[(rowb + t) * DI + d];
    float xv  = xib[(rowb + t) * DI + d];
    float zv  = zb[(rowb + t) * DI + d];
    float u = dtv * xv;
    float y = 0.0f;
#pragma unroll
    for (int q = 0; q < 4; ++q) {
      float4 Bq = *(const float4*)&sbc[t * 32 + q * 4];
      float4 Cq = *(const float4*)&sbc[t * 32 + 16 + q * 4];
      s[q * 4 + 0] = exp2f(dtv * A2[q * 4 + 0]) * s[q * 4 + 0] + u * Bq.x;
      y += s[q * 4 + 0] * Cq.x;
      s[q * 4 + 1] = exp2f(dtv * A2[q * 4 + 1]) * s[q * 4 + 1] + u * Bq.y;
      y += s[q * 4 + 1] * Cq.y;
      s[q * 4 + 2] = exp2f(dtv * A2[q * 4 + 2]) * s[q * 4 + 2] + u * Bq.z;
      y += s[q * 4 + 2] * Cq.z;
      s[q * 4 + 3] = exp2f(dtv * A2[q * 4 + 3]) * s[q * 4 + 3] + u * Bq.w;
      y += s[q * 4 + 3] * Cq.w;
    }
    float gt = zv * sigmoidf_(zv);
    dtb[(rowb + t) * DI + d] = (y + xv * Dv) * gt;
  }
}

// ---------------- Mamba K4: out_proj (64 out x 128 k) on gated activations; res +=
__global__ void __launch_bounds__(256, 2) k_outproj(const float* __restrict__ gt_g,
    const float* __restrict__ outw, float* __restrict__ res) {
  __shared__ float gt[64 * 128];
  __shared__ float4 w4s[32 * 64];
  int tid = threadIdx.x;
  int b = blockIdx.x >> 5;
  int t0 = (blockIdx.x & 31) * 64;
  size_t base = (size_t)(b * LQ + t0) * DI;
  const float4* src4 = (const float4*)(gt_g + base);
  for (int i = tid; i < 2048; i += 256)
    ((float4*)gt)[i] = src4[i];
  for (int i = tid; i < 2048; i += 256) {
    int c = i >> 5, kb = i & 31;
    w4s[kb * 64 + ((c + kb) & 63)] = ((const float4*)outw)[i];
  }
  __syncthreads();
  int wv = tid >> 6, lane = tid & 63;
  int r0 = wv * 16;
  float acc[16];
#pragma unroll
  for (int rr = 0; rr < 16; ++rr) acc[rr] = 0.0f;
#pragma unroll 2
  for (int kb = 0; kb < 32; ++kb) {
    float4 wvv = w4s[kb * 64 + ((lane + kb) & 63)];
#pragma unroll
    for (int rr = 0; rr < 16; ++rr) {
      float4 xv = *(const float4*)&gt[(r0 + rr) * 128 + kb * 4];
      acc[rr] += wvv.x * xv.x + wvv.y * xv.y + wvv.z * xv.z + wvv.w * xv.w;
    }
  }
#pragma unroll
  for (int rr = 0; rr < 16; ++rr)
    res[(size_t)(b * LQ + t0 + r0 + rr) * 64 + lane] += acc[rr];
}

// ---------------- Final LayerNorm: res -> hf, one wave per row
__global__ void __launch_bounds__(256) k_lnfinal(const float* __restrict__ res,
    const float* __restrict__ g, const float* __restrict__ bb, float* __restrict__ hf) {
  int row = blockIdx.x * 4 + (threadIdx.x >> 6);
  int lane = threadIdx.x & 63;
  float v = res[row * 64 + lane];
  float s = v;
#pragma unroll
  for (int m = 32; m >= 1; m >>= 1) s += __shfl_xor(s, m);
  float mean = s * (1.0f / 64.0f);
  float dd = v - mean;
  float q = dd * dd;
#pragma unroll
  for (int m = 32; m >= 1; m >>= 1) q += __shfl_xor(q, m);
  float iv = rsqrtf(q * (1.0f / 64.0f) + EPS);
  hf[row * 64 + lane] = dd * iv * g[lane] + bb[lane];
}

// ---------------- Classifier conv: 64->64 K=5 stride2 pad2 + BN + ReLU
__global__ void __launch_bounds__(256) k_cls(const float* __restrict__ in,
    float* __restrict__ out, const float* __restrict__ w,
    const float* __restrict__ bb, const float* __restrict__ g,
    const float* __restrict__ be, int Lin, int Lout, int layout) {
  __shared__ float xin[64 * 136];
  __shared__ float wl[16 * 320];
  int tid = threadIdx.x;
  int tilesPerB = Lout >> 6;
  int b = blockIdx.x / tilesPerB;
  int t0 = (blockIdx.x % tilesPerB) * 64;
  int lbase = 2 * t0 - 2;
  if (layout == 0) {
    for (int i = tid; i < 64 * 131; i += 256) {
      int lr = i >> 6, ci = i & 63;
      int l = lbase + lr;
      xin[ci * 136 + lr] = (l >= 0 && l < Lin) ? in[(b * Lin + l) * 64 + ci] : 0.0f;
    }
  } else {
    for (int i = tid; i < 64 * 132; i += 256) {
      int ci = i / 132, lr = i % 132;
      if (lr < 131) {
        int l = lbase + lr;
        xin[ci * 136 + lr] = (l >= 0 && l < Lin) ? in[(b * 64 + ci) * Lin + l] : 0.0f;
      }
    }
  }
  int wv = tid >> 6, lane = tid & 63;
  float rs = rsqrtf(1.0f + EPS);
  for (int p = 0; p < 4; ++p) {
    __syncthreads();
    for (int i = tid; i < 16 * 320; i += 256) wl[i] = w[p * 16 * 320 + i];
    __syncthreads();
    float acc[4] = {0.0f, 0.0f, 0.0f, 0.0f};
    for (int ci = 0; ci < 64; ++ci) {
      const float* xr = &xin[ci * 136 + 2 * lane];
      float v0 = xr[0], v1 = xr[1], v2 = xr[2], v3 = xr[3], v4 = xr[4];
      const float* wr = &wl[(wv * 4) * 320 + ci * 5];
#pragma unroll
      for (int i2 = 0; i2 < 4; ++i2) {
        acc[i2] += wr[i2 * 320 + 0] * v0 + wr[i2 * 320 + 1] * v1 + wr[i2 * 320 + 2] * v2
                 + wr[i2 * 320 + 3] * v3 + wr[i2 * 320 + 4] * v4;
      }
    }
#pragma unroll
    for (int i2 = 0; i2 < 4; ++i2) {
      int co = p * 16 + wv * 4 + i2;
      float v = (acc[i2] + bb[co]) * (g[co] * rs) + be[co];
      out[(b * 64 + co) * Lout + t0 + lane] = fmaxf(v, 0.0f);
    }
  }
}

// ---------------- fc1 weight transpose prep
__global__ void __launch_bounds__(256) k_prep_fc1(const float* __restrict__ w,
                                                  float* __restrict__ wt) {
  int i = blockIdx.x * 256 + threadIdx.x;   // i < 131072
  int kb = i >> 8, f = i & 255;
  ((float4*)wt)[i] = ((const float4*)w)[f * 512 + kb];
}

// ---------------- Pool + FC1 + BN + ReLU + FC2
__global__ void __launch_bounds__(256) k_fc(const float* __restrict__ cin,
    const float* __restrict__ w1t, const float* __restrict__ b1,
    const float* __restrict__ g, const float* __restrict__ be,
    const float* __restrict__ w2, const float* __restrict__ b2,
    float* __restrict__ dout) {
  __shared__ float pooled[2048];
  __shared__ float feat[256];
  int tid = threadIdx.x;
  int b = blockIdx.x;
  for (int i = tid; i < 2048; i += 256) {
    float4 v = ((const float4*)cin)[b * 2048 + i];
    pooled[i] = (v.x + v.y + v.z + v.w) * 0.25f;
  }
  __syncthreads();
  float acc = b1[tid];
  const float4* wt4 = (const float4*)w1t;
  for (int kb = 0; kb < 512; ++kb) {
    float4 wv = wt4[kb * 256 + tid];
    float4 pv = *(const float4*)&pooled[kb * 4];
    acc += wv.x * pv.x + wv.y * pv.y + wv.z * pv.z + wv.w * pv.w;
  }
  float v = acc * (g[tid] * rsqrtf(1.0f + EPS)) + be[tid];
  feat[tid] = fmaxf(v, 0.0f);
  __syncthreads();
  if (tid < 5) {
    float a2 = b2[tid];
    for (int k = 0; k < 256; ++k) a2 += w2[tid * 256 + k] * feat[k];
    dout[b * 5 + tid] = a2;
  }
}

extern "C" void kernel_launch(void* const* d_in, const int* in_sizes, int n_in,
                              void* d_out, int out_size, void* d_ws, size_t ws_size,
                              hipStream_t stream) {
  (void)in_sizes; (void)n_in; (void)out_size; (void)ws_size;
  const float* x      = (const float*)d_in[0];
  const float* dw1    = (const float*)d_in[1];
  const float* db1    = (const float*)d_in[2];
  const float* dg1    = (const float*)d_in[3];
  const float* dbe1   = (const float*)d_in[4];
  const float* dw2    = (const float*)d_in[5];
  const float* db2    = (const float*)d_in[6];
  const float* dg2    = (const float*)d_in[7];
  const float* dbe2   = (const float*)d_in[8];
  const float* lng    = (const float*)d_in[9];
  const float* lnb    = (const float*)d_in[10];
  const float* inw    = (const float*)d_in[11];
  const float* convw  = (const float*)d_in[12];
  const float* convb  = (const float*)d_in[13];
  const float* xprojw = (const float*)d_in[14];
  const float* dtpw   = (const float*)d_in[15];
  const float* dtpb   = (const float*)d_in[16];
  const float* alog   = (const float*)d_in[17];
  const float* Dp     = (const float*)d_in[18];
  const float* outw   = (const float*)d_in[19];
  const float* flng   = (const float*)d_in[20];
  const float* flnb   = (const float*)d_in[21];
  const float* clsw1  = (const float*)d_in[22];
  const float* clsb1  = (const float*)d_in[23];
  const float* clsg1  = (const float*)d_in[24];
  const float* clsbe1 = (const float*)d_in[25];
  const float* clswR  = (const float*)d_in[26];
  const float* clsbR  = (const float*)d_in[27];
  const float* clsgR  = (const float*)d_in[28];
  const float* clsbeR = (const float*)d_in[29];
  const float* fc1w   = (const float*)d_in[30];
  const float* fc1b   = (const float*)d_in[31];
  const float* fcg    = (const float*)d_in[32];
  const float* fcbe   = (const float*)d_in[33];
  const float* fc2w   = (const float*)d_in[34];
  const float* fc2b   = (const float*)d_in[35];

  float* ws = (float*)d_ws;
  float* h1    = ws;                    // (B,64,L); free during mamba -> fb lives here
  float* res   = ws + 2097152;          // (B,L,64)
  float* xiraw = ws + 4194304;          // (B,L,128)
  float* zb    = ws + 8388608;
  float* xib   = ws + 12582912;
  float* dtb   = ws + 16777216;         // dt -> gated y (in-place through scan)
  float* bcb   = ws + 20971520;         // (B,L,32)
  float* fc1t  = ws + 22020096;
  // scan temps: fb in h1 region (dead between k_conv2 and k_lnfinal);
  // Sb + sumdt in xiraw region (dead after k_convx)
  float* fb    = h1;                    // 16*64*128*16 = 2,097,152 floats
  float* Sb    = xiraw;                 // 2,097,152
  float* sumdt = xiraw + 2097152;       // 131,072
  float* c1 = xiraw;                    // classifier bufs reuse xiraw
  float* c2 = xiraw + 1048576;
  float* c3 = xiraw + 1572864;
  float* c4 = xiraw + 1835008;
  float* hf = h1;

  k_prep_fc1<<<512, 256, 0, stream>>>(fc1w, fc1t);
  k_front<<<8192, 256, 0, stream>>>(x, dw1, db1, dg1, dbe1, h1);
  k_conv2<<<512, 256, 0, stream>>>(h1, dw2, db2, dg2, dbe2, res);
  for (int il = 0; il < 4; ++il) {
    k_lnproj<<<512, 256, 0, stream>>>(res, lng + il * 64, lnb + il * 64,
                                      inw + il * 16384, xiraw, zb);
    k_convx<<<1024, 256, 0, stream>>>(xiraw, convw + il * 512, convb + il * 128,
                                      xprojw + il * 4608, dtpw + il * 512,
                                      dtpb + il * 128, xib, dtb, bcb);
    k_scan_p1<<<BN * NCH, 128, 0, stream>>>(dtb, xib, bcb, alog + il * 2048,
                                            sumdt, fb);
    k_scan_p2<<<128, 256, 0, stream>>>(sumdt, fb, alog + il * 2048, Sb);
    k_scan_p3<<<BN * NCH, 128, 0, stream>>>(dtb, xib, bcb, zb, Dp + il * 128,
                                            alog + il * 2048, Sb);
    k_outproj<<<512, 256, 0, stream>>>(dtb, outw + il * 8192, res);
  }
  k_lnfinal<<<8192, 256, 0, stream>>>(res, flng, flnb, hf);
  k_cls<<<256, 256, 0, stream>>>(hf, c1, clsw1, clsb1, clsg1, clsbe1, 2048, 1024, 0);
  k_cls<<<128, 256, 0, stream>>>(c1, c2, clswR + 0 * 20480, clsbR + 0, clsgR + 0,
                                 clsbeR + 0, 1024, 512, 1);
  k_cls<<<64, 256, 0, stream>>>(c2, c3, clswR + 1 * 20480, clsbR + 64, clsgR + 64,
                                clsbeR + 64, 512, 256, 1);
  k_cls<<<32, 256, 0, stream>>>(c3, c4, clswR + 2 * 20480, clsbR + 128, clsgR + 128,
                                clsbeR + 128, 256, 128, 1);
  k_fc<<<16, 256, 0, stream>>>(c4, fc1t, fc1b, fcg, fcbe, fc2w, fc2b, (float*)d_out);
}

// Round 6
// 1009.609 us; speedup vs baseline: 5.2955x; 1.0597x over previous
//
#include <hip/hip_runtime.h>

#define DINL static __device__ __forceinline__

namespace {
constexpr int BN = 16;
constexpr int LQ = 2048;
constexpr int DM = 64;
constexpr int DI = 128;
constexpr float EPS = 1e-5f;
constexpr int NCH = 64;   // scan chunks
constexpr int CT = 32;    // chunk length (NCH*CT == LQ)
constexpr float LOG2E = 1.4426950408889634f;
}

DINL float sigmoidf_(float x) { return 1.0f / (1.0f + __expf(-x)); }

// ---------------- Stage A: conv1d 1->64 K=3 pad1 + BN + ReLU -> h1 (B,64,L)
__global__ void __launch_bounds__(256) k_front(const float* __restrict__ x,
    const float* __restrict__ w, const float* __restrict__ bb,
    const float* __restrict__ g, const float* __restrict__ be,
    float* __restrict__ h1) {
  int idx = blockIdx.x * 256 + threadIdx.x;   // (b*64+c)*2048 + l
  int l = idx & (LQ - 1);
  int c = (idx >> 11) & 63;
  int b = idx >> 17;
  const float* xr = x + b * LQ;
  float xm = (l > 0) ? xr[l - 1] : 0.0f;
  float x0 = xr[l];
  float xp = (l < LQ - 1) ? xr[l + 1] : 0.0f;
  float acc = w[c * 3 + 0] * xm + w[c * 3 + 1] * x0 + w[c * 3 + 2] * xp + bb[c];
  float v = acc * (g[c] * rsqrtf(1.0f + EPS)) + be[c];
  h1[idx] = fmaxf(v, 0.0f);
}

// ---------------- Stage B: conv1d 64->64 K=3 pad1 + BN + ReLU, write transposed res (B,L,64)
__global__ void __launch_bounds__(256) k_conv2(const float* __restrict__ h1,
    const float* __restrict__ w, const float* __restrict__ bb,
    const float* __restrict__ g, const float* __restrict__ be,
    float* __restrict__ res) {
  __shared__ float xin[64 * 66];   // 64 ci x (64+2)
  __shared__ float wl[32 * 192];   // half the out channels per pass
  __shared__ float os[64 * 65];    // out staging (l, c) padded
  int tid = threadIdx.x;
  int b = blockIdx.x >> 5;
  int t0 = (blockIdx.x & 31) * 64;
  for (int i = tid; i < 64 * 66; i += 256) {
    int ci = i / 66, j = i % 66;
    int l = t0 - 1 + j;
    xin[i] = (l >= 0 && l < LQ) ? h1[(b * 64 + ci) * LQ + l] : 0.0f;
  }
  int wv = tid >> 6, lane = tid & 63;
  float rs = rsqrtf(1.0f + EPS);
  for (int p = 0; p < 2; ++p) {
    __syncthreads();
    for (int i = tid; i < 32 * 192; i += 256) wl[i] = w[p * 32 * 192 + i];
    __syncthreads();
    float acc[8];
#pragma unroll
    for (int i2 = 0; i2 < 8; ++i2) acc[i2] = 0.0f;
    for (int ci = 0; ci < 64; ++ci) {
      float x0 = xin[ci * 66 + lane];
      float x1 = xin[ci * 66 + lane + 1];
      float x2 = xin[ci * 66 + lane + 2];
      const float* wr = &wl[(wv * 8) * 192 + ci * 3];
#pragma unroll
      for (int i2 = 0; i2 < 8; ++i2)
        acc[i2] += wr[i2 * 192 + 0] * x0 + wr[i2 * 192 + 1] * x1 + wr[i2 * 192 + 2] * x2;
    }
#pragma unroll
    for (int i2 = 0; i2 < 8; ++i2) {
      int co = p * 32 + wv * 8 + i2;
      float v = (acc[i2] + bb[co]) * (g[co] * rs) + be[co];
      os[lane * 65 + co] = fmaxf(v, 0.0f);
    }
  }
  __syncthreads();
  for (int i = tid; i < 4096; i += 256) {
    int r = i >> 6, c = i & 63;
    res[(b * LQ + t0 + r) * 64 + c] = os[r * 65 + c];
  }
}

// ---------------- Mamba K1: LayerNorm + in_proj (256x64), split to xi_raw / z
__global__ void __launch_bounds__(256) k_lnproj(const float* __restrict__ res,
    const float* __restrict__ lng, const float* __restrict__ lnb,
    const float* __restrict__ inw, float* __restrict__ xiraw, float* __restrict__ zb) {
  __shared__ float tile[64 * 68];
  __shared__ float4 w4[16 * 128];
  __shared__ float gl[64], bl[64];
  int tid = threadIdx.x;
  int b = blockIdx.x >> 5;
  int t0 = (blockIdx.x & 31) * 64;
  const float4* rb0 = (const float4*)(res + (size_t)(b * LQ + t0) * 64);
  for (int i = tid; i < 1024; i += 256) {
    int r = i >> 4, kb = i & 15;
    *(float4*)&tile[r * 68 + kb * 4] = rb0[i];
  }
  if (tid < 64) gl[tid] = lng[tid];
  else if (tid < 128) bl[tid - 64] = lnb[tid - 64];
  __syncthreads();
  {
    int row = tid >> 2, part = tid & 3;
    float* tr = &tile[row * 68];
    float s = 0.0f;
#pragma unroll
    for (int k = 0; k < 16; ++k) s += tr[part + 4 * k];
    s += __shfl_xor(s, 1);
    s += __shfl_xor(s, 2);
    float m = s * (1.0f / 64.0f);
    float q = 0.0f;
#pragma unroll
    for (int k = 0; k < 16; ++k) { float dd = tr[part + 4 * k] - m; q += dd * dd; }
    q += __shfl_xor(q, 1);
    q += __shfl_xor(q, 2);
    float iv = rsqrtf(q * (1.0f / 64.0f) + EPS);
#pragma unroll
    for (int k = 0; k < 16; ++k) {
      int c = part + 4 * k;
      tr[c] = (tr[c] - m) * iv * gl[c] + bl[c];
    }
  }
  int ln = tid & 63, wv = tid >> 6;
  int rh = ln >> 5;
  int c0 = (ln & 31) * 4;
  int r0 = (wv * 2 + rh) * 8;
  const float4* wsrc = (const float4*)inw;
  for (int p = 0; p < 2; ++p) {
    __syncthreads();
    for (int i = tid; i < 2048; i += 256) {
      int c = i >> 4, kb = i & 15;
      w4[kb * 128 + c] = wsrc[p * 2048 + i];
    }
    __syncthreads();
    float acc[8][4];
#pragma unroll
    for (int rr = 0; rr < 8; ++rr)
#pragma unroll
      for (int cc = 0; cc < 4; ++cc) acc[rr][cc] = 0.0f;
#pragma unroll 2
    for (int kb = 0; kb < 16; ++kb) {
      float4 w0 = w4[kb * 128 + c0 + 0];
      float4 w1 = w4[kb * 128 + c0 + 1];
      float4 w2 = w4[kb * 128 + c0 + 2];
      float4 w3 = w4[kb * 128 + c0 + 3];
#pragma unroll
      for (int rr = 0; rr < 8; ++rr) {
        float4 xv = *(const float4*)&tile[(r0 + rr) * 68 + kb * 4];
        acc[rr][0] += w0.x * xv.x + w0.y * xv.y + w0.z * xv.z + w0.w * xv.w;
        acc[rr][1] += w1.x * xv.x + w1.y * xv.y + w1.z * xv.z + w1.w * xv.w;
        acc[rr][2] += w2.x * xv.x + w2.y * xv.y + w2.z * xv.z + w2.w * xv.w;
        acc[rr][3] += w3.x * xv.x + w3.y * xv.y + w3.z * xv.z + w3.w * xv.w;
      }
    }
    float* outp = (p == 0) ? xiraw : zb;
#pragma unroll
    for (int rr = 0; rr < 8; ++rr) {
      float4 o = make_float4(acc[rr][0], acc[rr][1], acc[rr][2], acc[rr][3]);
      *(float4*)&outp[(size_t)(b * LQ + t0 + r0 + rr) * DI + c0] = o;
    }
  }
}

// ---------------- Mamba K2: causal depthwise conv K=4 + SiLU + x_proj + dt_proj(softplus)
__global__ void __launch_bounds__(256) k_convx(const float* __restrict__ xiraw,
    const float* __restrict__ cw, const float* __restrict__ cb,
    const float* __restrict__ xw, const float* __restrict__ dtw,
    const float* __restrict__ dtbias, float* __restrict__ xib,
    float* __restrict__ dtb, float* __restrict__ bcb) {
  __shared__ float xin[35 * 128];
  __shared__ float xit[32 * 128];
  __shared__ float4 xw4[32 * 37];
  __shared__ float xdbl[32 * 40];
  __shared__ float4 cw4[128];
  __shared__ float cbl[128];
  __shared__ float4 dtw4[128];
  __shared__ float dtbl[128];
  int tid = threadIdx.x;
  int b = blockIdx.x >> 6;
  int t0 = (blockIdx.x & 63) * 32;
  for (int i = tid; i < 1120; i += 256) {
    int r = i >> 5, dq = i & 31;
    int l = t0 - 3 + r;
    float4 v = make_float4(0.f, 0.f, 0.f, 0.f);
    if (l >= 0) v = ((const float4*)xiraw)[(size_t)(b * LQ + l) * 32 + dq];
    *(float4*)&xin[r * 128 + dq * 4] = v;
  }
  if (tid < 128) {
    cw4[tid] = ((const float4*)cw)[tid];
    cbl[tid] = cb[tid];
    dtw4[tid] = ((const float4*)dtw)[tid];
    dtbl[tid] = dtbias[tid];
  }
  for (int i = tid; i < 32 * 36; i += 256) {
    xw4[(i & 31) * 37 + (i >> 5)] = ((const float4*)xw)[i];
  }
  __syncthreads();
  for (int i = tid; i < 32 * 128; i += 256) {
    int r = i >> 7, d = i & 127;
    float4 cv = cw4[d];
    float a = cbl[d] + cv.x * xin[r * 128 + d] + cv.y * xin[(r + 1) * 128 + d]
            + cv.z * xin[(r + 2) * 128 + d] + cv.w * xin[(r + 3) * 128 + d];
    float v = a * sigmoidf_(a);
    xit[i] = v;
    xib[(size_t)(b * LQ + t0 + r) * DI + d] = v;
  }
  __syncthreads();
  int wv = tid >> 6, lane = tid & 63;
  if (lane < 36) {
    int r0 = wv * 8;
    float acc[8];
#pragma unroll
    for (int rr = 0; rr < 8; ++rr) acc[rr] = 0.0f;
#pragma unroll 4
    for (int kb = 0; kb < 32; ++kb) {
      float4 wvv = xw4[kb * 37 + lane];
#pragma unroll
      for (int rr = 0; rr < 8; ++rr) {
        float4 xv = *(const float4*)&xit[(r0 + rr) * 128 + kb * 4];
        acc[rr] += wvv.x * xv.x + wvv.y * xv.y + wvv.z * xv.z + wvv.w * xv.w;
      }
    }
#pragma unroll
    for (int rr = 0; rr < 8; ++rr) xdbl[(r0 + rr) * 40 + lane] = acc[rr];
  }
  __syncthreads();
  for (int i = tid; i < 32 * 128; i += 256) {
    int r = i >> 7, d = i & 127;
    float4 wvv = dtw4[d];
    float4 xd = *(const float4*)&xdbl[r * 40];
    float sv = dtbl[d] + wvv.x * xd.x + wvv.y * xd.y + wvv.z * xd.z + wvv.w * xd.w;
    dtb[(size_t)(b * LQ + t0 + r) * DI + d] = (sv > 20.0f) ? sv : log1pf(__expf(sv));
  }
  for (int i = tid; i < 32 * 32; i += 256) {
    int r = i >> 5, j = i & 31;
    bcb[(size_t)(b * LQ + t0 + r) * 32 + j] = xdbl[r * 40 + 4 + j];
  }
}

// ---------------- Mamba K3a: chunk-local scan; states in registers
__global__ void __launch_bounds__(128) k_scan_p1(const float* __restrict__ dtb,
    const float* __restrict__ xib, const float* __restrict__ bcb,
    const float* __restrict__ alog, float* __restrict__ sumdt, float* __restrict__ fb) {
  __shared__ float sB[CT * 16];
  int blk = blockIdx.x;
  int c = blk & (NCH - 1), b = blk >> 6;
  int d = threadIdx.x;
  size_t rowb = (size_t)(b * LQ + c * CT);
  for (int i = d; i < CT * 4; i += 128) {
    int r = i >> 2, q = i & 3;
    ((float4*)sB)[i] = ((const float4*)bcb)[(rowb + r) * 8 + q];
  }
  float A2[16];
  const float4* al4 = (const float4*)alog;
#pragma unroll
  for (int q = 0; q < 4; ++q) {
    float4 a = al4[d * 4 + q];
    A2[q * 4 + 0] = -__expf(a.x) * LOG2E;
    A2[q * 4 + 1] = -__expf(a.y) * LOG2E;
    A2[q * 4 + 2] = -__expf(a.z) * LOG2E;
    A2[q * 4 + 3] = -__expf(a.w) * LOG2E;
  }
  float s[16];
#pragma unroll
  for (int j = 0; j < 16; ++j) s[j] = 0.0f;
  float sdt = 0.0f;
  __syncthreads();
#pragma unroll 2
  for (int t = 0; t < CT; ++t) {
    float dtv = dtb[(rowb + t) * DI + d];
    float xv  = xib[(rowb + t) * DI + d];
    sdt += dtv;
    float u = dtv * xv;
#pragma unroll
    for (int q = 0; q < 4; ++q) {
      float4 Bq = *(const float4*)&sB[t * 16 + q * 4];
      s[q * 4 + 0] = exp2f(dtv * A2[q * 4 + 0]) * s[q * 4 + 0] + u * Bq.x;
      s[q * 4 + 1] = exp2f(dtv * A2[q * 4 + 1]) * s[q * 4 + 1] + u * Bq.y;
      s[q * 4 + 2] = exp2f(dtv * A2[q * 4 + 2]) * s[q * 4 + 2] + u * Bq.z;
      s[q * 4 + 3] = exp2f(dtv * A2[q * 4 + 3]) * s[q * 4 + 3] + u * Bq.w;
    }
  }
  size_t ob = (size_t)(b * NCH + c) * DI + d;
  sumdt[ob] = sdt;
#pragma unroll
  for (int q = 0; q < 4; ++q) {
    float4 o = make_float4(s[q * 4 + 0], s[q * 4 + 1], s[q * 4 + 2], s[q * 4 + 3]);
    *(float4*)&fb[ob * 16 + q * 4] = o;
  }
}

// ---------------- Mamba K3b: sequential combine over chunks -> chunk-start states
__global__ void __launch_bounds__(256) k_scan_p2(const float* __restrict__ sumdt,
    const float* __restrict__ fb, const float* __restrict__ alog,
    float* __restrict__ Sb) {
  int idx = blockIdx.x * 256 + threadIdx.x;   // < 16*128*16
  int j = idx & 15, d = (idx >> 4) & 127, b = idx >> 11;
  float A2 = -__expf(alog[d * 16 + j]) * LOG2E;
  float s = 0.0f;
  for (int c = 0; c < NCH; ++c) {
    size_t base = (size_t)(b * NCH + c) * DI + d;
    Sb[base * 16 + j] = s;
    s = exp2f(A2 * sumdt[base]) * s + fb[base * 16 + j];
  }
}

// ---------------- Mamba K3c: re-run recurrence from Sstart; emit GATED y into dtb
__global__ void __launch_bounds__(128) k_scan_p3(float* __restrict__ dtb,
    const float* __restrict__ xib, const float* __restrict__ bcb,
    const float* __restrict__ zb, const float* __restrict__ Dpl,
    const float* __restrict__ alog, const float* __restrict__ Sb) {
  __shared__ float sbc[CT * 32];
  int blk = blockIdx.x;
  int c = blk & (NCH - 1), b = blk >> 6;
  int d = threadIdx.x;
  size_t rowb = (size_t)(b * LQ + c * CT);
  for (int i = d; i < CT * 8; i += 128)
    ((float4*)sbc)[i] = ((const float4*)bcb)[rowb * 8 + i];
  float A2[16];
  const float4* al4 = (const float4*)alog;
#pragma unroll
  for (int q = 0; q < 4; ++q) {
    float4 a = al4[d * 4 + q];
    A2[q * 4 + 0] = -__expf(a.x) * LOG2E;
    A2[q * 4 + 1] = -__expf(a.y) * LOG2E;
    A2[q * 4 + 2] = -__expf(a.z) * LOG2E;
    A2[q * 4 + 3] = -__expf(a.w) * LOG2E;
  }
  float Dv = Dpl[d];
  float s[16];
  size_t ob = ((size_t)(b * NCH + c) * DI + d) * 16;
#pragma unroll
  for (int q = 0; q < 4; ++q) {
    float4 v = *(const float4*)&Sb[ob + q * 4];
    s[q * 4 + 0] = v.x; s[q * 4 + 1] = v.y; s[q * 4 + 2] = v.z; s[q * 4 + 3] = v.w;
  }
  __syncthreads();
#pragma unroll 2
  for (int t = 0; t < CT; ++t) {
    float dtv = dtb[(rowb + t) * DI + d];
    float xv  = xib[(rowb + t) * DI + d];
    float zv  = zb[(rowb + t) * DI + d];
    float u = dtv * xv;
    float y = 0.0f;
#pragma unroll
    for (int q = 0; q < 4; ++q) {
      float4 Bq = *(const float4*)&sbc[t * 32 + q * 4];
      float4 Cq = *(const float4*)&sbc[t * 32 + 16 + q * 4];
      s[q * 4 + 0] = exp2f(dtv * A2[q * 4 + 0]) * s[q * 4 + 0] + u * Bq.x;
      y += s[q * 4 + 0] * Cq.x;
      s[q * 4 + 1] = exp2f(dtv * A2[q * 4 + 1]) * s[q * 4 + 1] + u * Bq.y;
      y += s[q * 4 + 1] * Cq.y;
      s[q * 4 + 2] = exp2f(dtv * A2[q * 4 + 2]) * s[q * 4 + 2] + u * Bq.z;
      y += s[q * 4 + 2] * Cq.z;
      s[q * 4 + 3] = exp2f(dtv * A2[q * 4 + 3]) * s[q * 4 + 3] + u * Bq.w;
      y += s[q * 4 + 3] * Cq.w;
    }
    float gt = zv * sigmoidf_(zv);
    dtb[(rowb + t) * DI + d] = (y + xv * Dv) * gt;
  }
}

// ---------------- Mamba K4: out_proj (64 out x 128 k) on gated activations; res +=
__global__ void __launch_bounds__(256, 2) k_outproj(const float* __restrict__ gt_g,
    const float* __restrict__ outw, float* __restrict__ res) {
  __shared__ float gt[64 * 128];
  __shared__ float4 w4s[32 * 64];
  int tid = threadIdx.x;
  int b = blockIdx.x >> 5;
  int t0 = (blockIdx.x & 31) * 64;
  size_t base = (size_t)(b * LQ + t0) * DI;
  const float4* src4 = (const float4*)(gt_g + base);
  for (int i = tid; i < 2048; i += 256)
    ((float4*)gt)[i] = src4[i];
  for (int i = tid; i < 2048; i += 256) {
    int c = i >> 5, kb = i & 31;
    w4s[kb * 64 + ((c + kb) & 63)] = ((const float4*)outw)[i];
  }
  __syncthreads();
  int wv = tid >> 6, lane = tid & 63;
  int r0 = wv * 16;
  float acc[16];
#pragma unroll
  for (int rr = 0; rr < 16; ++rr) acc[rr] = 0.0f;
#pragma unroll 2
  for (int kb = 0; kb < 32; ++kb) {
    float4 wvv = w4s[kb * 64 + ((lane + kb) & 63)];
#pragma unroll
    for (int rr = 0; rr < 16; ++rr) {
      float4 xv = *(const float4*)&gt[(r0 + rr) * 128 + kb * 4];
      acc[rr] += wvv.x * xv.x + wvv.y * xv.y + wvv.z * xv.z + wvv.w * xv.w;
    }
  }
#pragma unroll
  for (int rr = 0; rr < 16; ++rr)
    res[(size_t)(b * LQ + t0 + r0 + rr) * 64 + lane] += acc[rr];
}

// ---------------- Final LayerNorm: res -> hf, one wave per row
__global__ void __launch_bounds__(256) k_lnfinal(const float* __restrict__ res,
    const float* __restrict__ g, const float* __restrict__ bb, float* __restrict__ hf) {
  int row = blockIdx.x * 4 + (threadIdx.x >> 6);
  int lane = threadIdx.x & 63;
  float v = res[row * 64 + lane];
  float s = v;
#pragma unroll
  for (int m = 32; m >= 1; m >>= 1) s += __shfl_xor(s, m);
  float mean = s * (1.0f / 64.0f);
  float dd = v - mean;
  float q = dd * dd;
#pragma unroll
  for (int m = 32; m >= 1; m >>= 1) q += __shfl_xor(q, m);
  float iv = rsqrtf(q * (1.0f / 64.0f) + EPS);
  hf[row * 64 + lane] = dd * iv * g[lane] + bb[lane];
}

// ---------------- Classifier conv: 64->64 K=5 stride2 pad2 + BN + ReLU
// One pass per block: 16 out-channels (cg) x 64 L. Even/odd LDS split (stride 67)
// makes all compute reads conflict-free. layout 0: (B,Lin,64); 1: (B,64,Lin).
__global__ void __launch_bounds__(256) k_cls(const float* __restrict__ in,
    float* __restrict__ out, const float* __restrict__ w,
    const float* __restrict__ bb, const float* __restrict__ g,
    const float* __restrict__ be, int Lin, int Lout, int layout) {
  __shared__ float ev[64 * 67];   // even l offsets: j=0..65
  __shared__ float od[64 * 67];   // odd  l offsets: j=0..64
  __shared__ float wl[16 * 320];
  int tid = threadIdx.x;
  int cg = blockIdx.x & 3;
  int rest = blockIdx.x >> 2;
  int tilesPerB = Lout >> 6;
  int b = rest / tilesPerB;
  int t0 = (rest % tilesPerB) * 64;
  int lbase = 2 * t0 - 2;
  if (layout == 0) {
    for (int i = tid; i < 64 * 131; i += 256) {
      int lr = i >> 6, ci = i & 63;           // ci fast: coalesced global read
      int l = lbase + lr;
      float v = (l >= 0 && l < Lin) ? in[(b * Lin + l) * 64 + ci] : 0.0f;
      if (lr & 1) od[ci * 67 + (lr >> 1)] = v;
      else        ev[ci * 67 + (lr >> 1)] = v;
    }
  } else {
    for (int i = tid; i < 64 * 132; i += 256) {
      int ci = i / 132, lr = i % 132;         // lr fast: coalesced global read
      if (lr < 131) {
        int l = lbase + lr;
        float v = (l >= 0 && l < Lin) ? in[(b * 64 + ci) * Lin + l] : 0.0f;
        if (lr & 1) od[ci * 67 + (lr >> 1)] = v;
        else        ev[ci * 67 + (lr >> 1)] = v;
      }
    }
  }
  for (int i = tid; i < 16 * 320; i += 256) wl[i] = w[(cg * 16) * 320 + i];
  __syncthreads();
  int wv = tid >> 6, lane = tid & 63;
  float rs = rsqrtf(1.0f + EPS);
  float acc[4] = {0.0f, 0.0f, 0.0f, 0.0f};
  for (int ci = 0; ci < 64; ++ci) {
    float v0 = ev[ci * 67 + lane];
    float v1 = od[ci * 67 + lane];
    float v2 = ev[ci * 67 + lane + 1];
    float v3 = od[ci * 67 + lane + 1];
    float v4 = ev[ci * 67 + lane + 2];
    const float* wr = &wl[(wv * 4) * 320 + ci * 5];
#pragma unroll
    for (int i2 = 0; i2 < 4; ++i2) {
      acc[i2] += wr[i2 * 320 + 0] * v0 + wr[i2 * 320 + 1] * v1 + wr[i2 * 320 + 2] * v2
               + wr[i2 * 320 + 3] * v3 + wr[i2 * 320 + 4] * v4;
    }
  }
#pragma unroll
  for (int i2 = 0; i2 < 4; ++i2) {
    int co = cg * 16 + wv * 4 + i2;
    float v = (acc[i2] + bb[co]) * (g[co] * rs) + be[co];
    out[(b * 64 + co) * Lout + t0 + lane] = fmaxf(v, 0.0f);
  }
}

// ---------------- fc1 weight transpose prep
__global__ void __launch_bounds__(256) k_prep_fc1(const float* __restrict__ w,
                                                  float* __restrict__ wt) {
  int i = blockIdx.x * 256 + threadIdx.x;   // i < 131072
  int kb = i >> 8, f = i & 255;
  ((float4*)wt)[i] = ((const float4*)w)[f * 512 + kb];
}

// ---------------- Pool + FC1 + BN + ReLU + FC2
__global__ void __launch_bounds__(256) k_fc(const float* __restrict__ cin,
    const float* __restrict__ w1t, const float* __restrict__ b1,
    const float* __restrict__ g, const float* __restrict__ be,
    const float* __restrict__ w2, const float* __restrict__ b2,
    float* __restrict__ dout) {
  __shared__ float pooled[2048];
  __shared__ float feat[256];
  int tid = threadIdx.x;
  int b = blockIdx.x;
  for (int i = tid; i < 2048; i += 256) {
    float4 v = ((const float4*)cin)[b * 2048 + i];
    pooled[i] = (v.x + v.y + v.z + v.w) * 0.25f;
  }
  __syncthreads();
  float acc = b1[tid];
  const float4* wt4 = (const float4*)w1t;
  for (int kb = 0; kb < 512; ++kb) {
    float4 wv = wt4[kb * 256 + tid];
    float4 pv = *(const float4*)&pooled[kb * 4];
    acc += wv.x * pv.x + wv.y * pv.y + wv.z * pv.z + wv.w * pv.w;
  }
  float v = acc * (g[tid] * rsqrtf(1.0f + EPS)) + be[tid];
  feat[tid] = fmaxf(v, 0.0f);
  __syncthreads();
  if (tid < 5) {
    float a2 = b2[tid];
    for (int k = 0; k < 256; ++k) a2 += w2[tid * 256 + k] * feat[k];
    dout[b * 5 + tid] = a2;
  }
}

extern "C" void kernel_launch(void* const* d_in, const int* in_sizes, int n_in,
                              void* d_out, int out_size, void* d_ws, size_t ws_size,
                              hipStream_t stream) {
  (void)in_sizes; (void)n_in; (void)out_size; (void)ws_size;
  const float* x      = (const float*)d_in[0];
  const float* dw1    = (const float*)d_in[1];
  const float* db1    = (const float*)d_in[2];
  const float* dg1    = (const float*)d_in[3];
  const float* dbe1   = (const float*)d_in[4];
  const float* dw2    = (const float*)d_in[5];
  const float* db2    = (const float*)d_in[6];
  const float* dg2    = (const float*)d_in[7];
  const float* dbe2   = (const float*)d_in[8];
  const float* lng    = (const float*)d_in[9];
  const float* lnb    = (const float*)d_in[10];
  const float* inw    = (const float*)d_in[11];
  const float* convw  = (const float*)d_in[12];
  const float* convb  = (const float*)d_in[13];
  const float* xprojw = (const float*)d_in[14];
  const float* dtpw   = (const float*)d_in[15];
  const float* dtpb   = (const float*)d_in[16];
  const float* alog   = (const float*)d_in[17];
  const float* Dp     = (const float*)d_in[18];
  const float* outw   = (const float*)d_in[19];
  const float* flng   = (const float*)d_in[20];
  const float* flnb   = (const float*)d_in[21];
  const float* clsw1  = (const float*)d_in[22];
  const float* clsb1  = (const float*)d_in[23];
  const float* clsg1  = (const float*)d_in[24];
  const float* clsbe1 = (const float*)d_in[25];
  const float* clswR  = (const float*)d_in[26];
  const float* clsbR  = (const float*)d_in[27];
  const float* clsgR  = (const float*)d_in[28];
  const float* clsbeR = (const float*)d_in[29];
  const float* fc1w   = (const float*)d_in[30];
  const float* fc1b   = (const float*)d_in[31];
  const float* fcg    = (const float*)d_in[32];
  const float* fcbe   = (const float*)d_in[33];
  const float* fc2w   = (const float*)d_in[34];
  const float* fc2b   = (const float*)d_in[35];

  float* ws = (float*)d_ws;
  float* h1    = ws;                    // (B,64,L); free during mamba -> fb lives here
  float* res   = ws + 2097152;          // (B,L,64)
  float* xiraw = ws + 4194304;          // (B,L,128)
  float* zb    = ws + 8388608;
  float* xib   = ws + 12582912;
  float* dtb   = ws + 16777216;         // dt -> gated y (in-place through scan)
  float* bcb   = ws + 20971520;         // (B,L,32)
  float* fc1t  = ws + 22020096;
  float* fb    = h1;                    // scan temp
  float* Sb    = xiraw;
  float* sumdt = xiraw + 2097152;
  float* c1 = xiraw;                    // classifier bufs reuse xiraw
  float* c2 = xiraw + 1048576;
  float* c3 = xiraw + 1572864;
  float* c4 = xiraw + 1835008;
  float* hf = h1;

  k_prep_fc1<<<512, 256, 0, stream>>>(fc1w, fc1t);
  k_front<<<8192, 256, 0, stream>>>(x, dw1, db1, dg1, dbe1, h1);
  k_conv2<<<512, 256, 0, stream>>>(h1, dw2, db2, dg2, dbe2, res);
  for (int il = 0; il < 4; ++il) {
    k_lnproj<<<512, 256, 0, stream>>>(res, lng + il * 64, lnb + il * 64,
                                      inw + il * 16384, xiraw, zb);
    k_convx<<<1024, 256, 0, stream>>>(xiraw, convw + il * 512, convb + il * 128,
                                      xprojw + il * 4608, dtpw + il * 512,
                                      dtpb + il * 128, xib, dtb, bcb);
    k_scan_p1<<<BN * NCH, 128, 0, stream>>>(dtb, xib, bcb, alog + il * 2048,
                                            sumdt, fb);
    k_scan_p2<<<128, 256, 0, stream>>>(sumdt, fb, alog + il * 2048, Sb);
    k_scan_p3<<<BN * NCH, 128, 0, stream>>>(dtb, xib, bcb, zb, Dp + il * 128,
                                            alog + il * 2048, Sb);
    k_outproj<<<512, 256, 0, stream>>>(dtb, outw + il * 8192, res);
  }
  k_lnfinal<<<8192, 256, 0, stream>>>(res, flng, flnb, hf);
  k_cls<<<16 * 16 * 4, 256, 0, stream>>>(hf, c1, clsw1, clsb1, clsg1, clsbe1,
                                         2048, 1024, 0);
  k_cls<<<16 * 8 * 4, 256, 0, stream>>>(c1, c2, clswR + 0 * 20480, clsbR + 0,
                                        clsgR + 0, clsbeR + 0, 1024, 512, 1);
  k_cls<<<16 * 4 * 4, 256, 0, stream>>>(c2, c3, clswR + 1 * 20480, clsbR + 64,
                                        clsgR + 64, clsbeR + 64, 512, 256, 1);
  k_cls<<<16 * 2 * 4, 256, 0, stream>>>(c3, c4, clswR + 2 * 20480, clsbR + 128,
                                        clsgR + 128, clsbeR + 128, 256, 128, 1);
  k_fc<<<16, 256, 0, stream>>>(c4, fc1t, fc1b, fcg, fcbe, fc2w, fc2b, (float*)d_out);
}